// Round 7
// baseline (822.237 us; speedup 1.0000x reference)
//
#include <hip/hip_runtime.h>
#include <hip/hip_bf16.h>

// ---------------------------------------------------------------------------
// CompGCN layer:
//   bf16 data plane; coarse-bucket (128 keys) counting sort with LDS-staged
//   histogram/rank (kills partial-line write amplification), per-bucket LDS
//   f32 aggregation, bf16-MFMA fused 3-way GEMM with BN-stats epilogue,
//   BN apply + ReLU, out_rel = rel @ w_rel.
// ---------------------------------------------------------------------------

#define SCAN_BLOCK 256
#define CB 128               // keys per coarse bucket
#define CHUNK 8192           // edges per hist/rank block
#define NBC_MAX 800          // >= ceil(2V/CB) = 782

typedef __attribute__((ext_vector_type(8))) short short8v;   // 8 bf16
typedef __attribute__((ext_vector_type(4))) float float4v;   // MFMA C/D

__device__ inline short f2bf(float f) {
    union { float f; unsigned u; } c; c.f = f;
    unsigned u = c.u;
    return (short)((u + 0x7fffu + ((u >> 16) & 1u)) >> 16);  // RNE
}
__device__ inline float bflo(unsigned u) { return __uint_as_float(u << 16); }
__device__ inline float bfhi(unsigned u) { return __uint_as_float(u & 0xffff0000u); }

// cast x [V,128] and rel [R,128] to bf16, 8 elems/thread
__global__ __launch_bounds__(256) void xcast_kernel(
    const float* __restrict__ x, const float* __restrict__ rel,
    short* __restrict__ xbf, short* __restrict__ relbf, int V, int R)
{
    size_t i = ((size_t)blockIdx.x * 256 + threadIdx.x) * 8;
    size_t nx = (size_t)V * 128;
    size_t total = nx + (size_t)R * 128;
    if (i >= total) return;
    const float* sp; short* dp; size_t k;
    if (i < nx) { sp = x; dp = xbf; k = i; }
    else        { sp = rel; dp = relbf; k = i - nx; }
    float4 v0 = *reinterpret_cast<const float4*>(sp + k);
    float4 v1 = *reinterpret_cast<const float4*>(sp + k + 4);
    short8v o;
    o[0] = f2bf(v0.x); o[1] = f2bf(v0.y); o[2] = f2bf(v0.z); o[3] = f2bf(v0.w);
    o[4] = f2bf(v1.x); o[5] = f2bf(v1.y); o[6] = f2bf(v1.z); o[7] = f2bf(v1.w);
    *reinterpret_cast<short8v*>(dp + k) = o;
}

// per-block LDS histogram over coarse buckets; counts stored bucket-major
// counts[b*NBLK + blk]; no global atomics.
__global__ __launch_bounds__(256) void hist_coarse_kernel(
    const int* __restrict__ dst, int* __restrict__ counts,
    int E, int V, int NBC, int NBLK)
{
    __shared__ int lh[NBC_MAX];
    for (int i = threadIdx.x; i < NBC; i += 256) lh[i] = 0;
    __syncthreads();
    int half = E >> 1;
    int e0 = blockIdx.x * CHUNK;
#pragma unroll 4
    for (int i = 0; i < CHUNK / 256; ++i) {
        int e = e0 + i * 256 + threadIdx.x;
        if (e < E) {
            int key = dst[e] + (e < half ? 0 : V);
            atomicAdd(&lh[key >> 7], 1);
        }
    }
    __syncthreads();
    for (int i = threadIdx.x; i < NBC; i += 256)
        counts[(size_t)i * NBLK + blockIdx.x] = lh[i];
}

__global__ __launch_bounds__(SCAN_BLOCK) void scan_partial_kernel(
    const int* __restrict__ cnt, int* __restrict__ partials, int N)
{
    __shared__ int red[SCAN_BLOCK];
    int i = blockIdx.x * SCAN_BLOCK + threadIdx.x;
    red[threadIdx.x] = (i < N) ? cnt[i] : 0;
    __syncthreads();
    for (int s = SCAN_BLOCK / 2; s > 0; s >>= 1) {
        if (threadIdx.x < s) red[threadIdx.x] += red[threadIdx.x + s];
        __syncthreads();
    }
    if (threadIdx.x == 0) partials[blockIdx.x] = red[0];
}

__global__ __launch_bounds__(1024) void scan_top_kernel(
    int* __restrict__ partials, int NB)
{
    __shared__ int sh[1024];
    int t = threadIdx.x;
    sh[t] = (t < NB) ? partials[t] : 0;
    __syncthreads();
    for (int s = 1; s < 1024; s <<= 1) {
        int v = (t >= s) ? sh[t - s] : 0;
        __syncthreads();
        sh[t] += v;
        __syncthreads();
    }
    if (t < NB) partials[t] = (t == 0) ? 0 : sh[t - 1];
}

__global__ __launch_bounds__(SCAN_BLOCK) void scan_final_kernel(
    const int* __restrict__ cnt, const int* __restrict__ partials,
    int* __restrict__ base, int N)
{
    __shared__ int sh[SCAN_BLOCK];
    int i = blockIdx.x * SCAN_BLOCK + threadIdx.x;
    int t = threadIdx.x;
    int v = (i < N) ? cnt[i] : 0;
    sh[t] = v;
    __syncthreads();
    for (int s = 1; s < SCAN_BLOCK; s <<= 1) {
        int u = (t >= s) ? sh[t - s] : 0;
        __syncthreads();
        sh[t] += u;
        __syncthreads();
    }
    if (i < N) base[i] = partials[blockIdx.x] + sh[t] - v;
}

// scatter payload; per-(block,bucket) runs are contiguous and written from one
// CU -> lines fill while L2-resident (low write amplification).
// payload: (src<<16 | type<<8 | key&127, norm-bits)
__global__ __launch_bounds__(256) void rank_coarse_kernel(
    const int* __restrict__ dst,
    const int* __restrict__ src,
    const int* __restrict__ edge_type,
    const float* __restrict__ edge_norm,
    const int* __restrict__ base,
    uint2* __restrict__ pay,
    int E, int V, int NBC, int NBLK)
{
    __shared__ int lh[NBC_MAX];
    __shared__ int lb[NBC_MAX];
    for (int i = threadIdx.x; i < NBC; i += 256) {
        lh[i] = 0;
        lb[i] = base[(size_t)i * NBLK + blockIdx.x];
    }
    __syncthreads();
    int half = E >> 1;
    int e0 = blockIdx.x * CHUNK;
#pragma unroll 4
    for (int i = 0; i < CHUNK / 256; ++i) {
        int e = e0 + i * 256 + threadIdx.x;
        if (e < E) {
            int d = dst[e], s = src[e], t = edge_type[e];
            float n = edge_norm[e];
            int key = d + (e < half ? 0 : V);
            int b = key >> 7;
            int r = atomicAdd(&lh[b], 1);
            pay[lb[b] + r] = make_uint2(
                ((unsigned)s << 16) | ((unsigned)t << 8) | (unsigned)(key & 127),
                __float_as_uint(n));
        }
    }
}

// one block per coarse bucket: LDS f32 accumulator [128 keys][128 feats],
// coalesced payload reads, bf16 row gathers, LDS atomics, coalesced writeout.
__global__ __launch_bounds__(256) void aggregate_coarse_kernel(
    const short* __restrict__ xbf,
    const short* __restrict__ relbf,
    const uint2* __restrict__ pay,
    const int* __restrict__ base,
    short* __restrict__ accbf,       // [NK,128]
    int E, int NK, int NBC, int NBLK)
{
    __shared__ float lacc[CB * 128];    // 64 KB
    int b = blockIdx.x;
    for (int i = threadIdx.x; i < CB * 128; i += 256) lacc[i] = 0.f;

    int beg = base[(size_t)b * NBLK];
    int end = (b + 1 < NBC) ? base[(size_t)(b + 1) * NBLK] : E;
    __syncthreads();

    int gid  = threadIdx.x >> 5;     // 8 groups of 32 lanes
    int lane = threadIdx.x & 31;
    int f0 = lane << 2;

    for (int bas = beg + gid * 32; bas < end; bas += 8 * 32) {
        int j = bas + lane;
        uint2 p = (j < end) ? pay[j] : make_uint2(0u, 0u);
        int m = min(32, end - bas);
        for (int q = 0; q < m; ++q) {
            unsigned pq = __shfl(p.x, q, 32);
            float nq = __uint_as_float(__shfl(p.y, q, 32));
            int s = (int)(pq >> 16);
            int t = (int)((pq >> 8) & 0xffu);
            int k = (int)(pq & 0x7fu);
            uint2 xv = *reinterpret_cast<const uint2*>(xbf + (size_t)s * 128 + f0);
            uint2 rv = *reinterpret_cast<const uint2*>(relbf + (size_t)t * 128 + f0);
            float* row = &lacc[k * 128 + f0];
            atomicAdd(row + 0, bflo(xv.x) * bflo(rv.x) * nq);
            atomicAdd(row + 1, bfhi(xv.x) * bfhi(rv.x) * nq);
            atomicAdd(row + 2, bflo(xv.y) * bflo(rv.y) * nq);
            atomicAdd(row + 3, bfhi(xv.y) * bfhi(rv.y) * nq);
        }
    }
    __syncthreads();

    // write out CB rows x 128 cols as bf16 (uint2 = 4 bf16), coalesced
    for (int u = threadIdx.x; u < CB * 32; u += 256) {
        int row = u >> 5;
        int c4  = (u & 31) << 2;
        int key = b * CB + row;
        if (key < NK) {
            float v0 = lacc[row * 128 + c4 + 0];
            float v1 = lacc[row * 128 + c4 + 1];
            float v2 = lacc[row * 128 + c4 + 2];
            float v3 = lacc[row * 128 + c4 + 3];
            uint2 o;
            o.x = (unsigned)(unsigned short)f2bf(v0) | ((unsigned)(unsigned short)f2bf(v1) << 16);
            o.y = (unsigned)(unsigned short)f2bf(v2) | ((unsigned)(unsigned short)f2bf(v3) << 16);
            *reinterpret_cast<uint2*>(accbf + (size_t)key * 128 + c4) = o;
        }
    }
}

// pack weights into bf16 MFMA B-fragment order; loop_rel folded into loop_w
__global__ __launch_bounds__(256) void wpack_kernel(
    const float* __restrict__ in_w,
    const float* __restrict__ out_w,
    const float* __restrict__ loop_w,
    const float* __restrict__ loop_rel,
    short* __restrict__ wpack)
{
    int idx = blockIdx.x * 256 + threadIdx.x;
    if (idx >= 3 * 8 * 4 * 64) return;
    int lane = idx & 63;
    int t    = (idx >> 6) & 3;
    int cblk = (idx >> 8) & 7;
    int m    = idx >> 11;
    const float* W = (m == 0) ? in_w : (m == 1) ? out_w : loop_w;
    int col = cblk * 16 + (lane & 15);
    int kb  = t * 32 + ((lane >> 4) << 3);
    short8v v;
#pragma unroll
    for (int j = 0; j < 8; ++j) {
        float w = W[(kb + j) * 128 + col];
        if (m == 2) w *= loop_rel[kb + j];
        v[j] = f2bf(w);
    }
    *reinterpret_cast<short8v*>(wpack + (size_t)idx * 8) = v;
}

// bf16 MFMA fused GEMM + bias + /3, BN stats fused into epilogue
__global__ __launch_bounds__(256) void fused_gemm_mfma_kernel(
    const short* __restrict__ accbf,     // [2V,128]
    const short* __restrict__ xbf,       // [V,128]
    const short* __restrict__ wpack,
    const float* __restrict__ bias,
    float* __restrict__ h,
    float* __restrict__ stats,           // [0:128] sum, [128:256] sumsq
    int V)
{
    __shared__ float s_red[256];

    int wave = threadIdx.x >> 6;
    int lane = threadIdx.x & 63;
    int kgrp = lane >> 4;
    int row0 = blockIdx.x * 64 + wave * 16;
    int rowl = row0 + (lane & 15);
    int rowc = min(rowl, V - 1);          // clamp (stores guarded)

    for (int i = threadIdx.x; i < 256; i += 256) s_red[i] = 0.f;

    float4v c[8];
#pragma unroll
    for (int b = 0; b < 8; ++b) c[b] = (float4v)(0.f);

    const short* mats[3] = { accbf, accbf + (size_t)V * 128, xbf };

    for (int m = 0; m < 3; ++m) {
        const short* A = mats[m] + (size_t)rowc * 128;
#pragma unroll
        for (int t = 0; t < 4; ++t) {
            short8v af = *reinterpret_cast<const short8v*>(A + t * 32 + (kgrp << 3));
            const short* wp = wpack + (((size_t)(m * 8) * 4 + t) * 64 + lane) * 8;
#pragma unroll
            for (int b = 0; b < 8; ++b) {
                short8v bf_ = *reinterpret_cast<const short8v*>(wp + (size_t)b * 4 * 64 * 8);
                c[b] = __builtin_amdgcn_mfma_f32_16x16x32_bf16(af, bf_, c[b], 0, 0, 0);
            }
        }
    }
    __syncthreads();   // s_red zeroed

    // epilogue: C/D layout col=lane&15, row=(lane>>4)*4+r  [m89]
#pragma unroll
    for (int b = 0; b < 8; ++b) {
        int col = b * 16 + (lane & 15);
        float bv = bias[col];
        float ps = 0.f, pq = 0.f;
#pragma unroll
        for (int r = 0; r < 4; ++r) {
            int row = row0 + kgrp * 4 + r;
            if (row < V) {
                float v = c[b][r] * (1.f / 3.f) + bv;
                h[(size_t)row * 128 + col] = v;
                ps += v;
                pq += v * v;
            }
        }
        atomicAdd(&s_red[col], ps);
        atomicAdd(&s_red[128 + col], pq);
    }
    __syncthreads();
    if (threadIdx.x < 256)
        atomicAdd(&stats[threadIdx.x], s_red[threadIdx.x]);
}

__global__ __launch_bounds__(256) void bn_apply_kernel(
    float* __restrict__ h,
    const float* __restrict__ stats,
    const float* __restrict__ gamma,
    const float* __restrict__ beta,
    int V)
{
    int col = threadIdx.x & 127;
    int rg  = threadIdx.x >> 7;
    float inv_v = 1.f / (float)V;
    float mean = stats[col] * inv_v;
    float var  = stats[128 + col] * inv_v - mean * mean;
    float sc = rsqrtf(var + 1e-5f) * gamma[col];
    float sh = beta[col] - mean * sc;
    for (int row = blockIdx.x * 2 + rg; row < V; row += gridDim.x * 2) {
        float v = h[(size_t)row * 128 + col];
        v = v * sc + sh;
        h[(size_t)row * 128 + col] = v > 0.f ? v : 0.f;
    }
}

__global__ __launch_bounds__(256) void rel_gemm_kernel(
    const float* __restrict__ rel,
    const float* __restrict__ w_rel,
    float* __restrict__ out_rel,
    int R)
{
    int col = threadIdx.x & 127;
    int row = blockIdx.x * 2 + (threadIdx.x >> 7);
    if (row >= R) return;
    float acc = 0.f;
    for (int k = 0; k < 128; ++k)
        acc += rel[row * 128 + k] * w_rel[k * 128 + col];
    out_rel[row * 128 + col] = acc;
}

extern "C" void kernel_launch(void* const* d_in, const int* in_sizes, int n_in,
                              void* d_out, int out_size, void* d_ws, size_t ws_size,
                              hipStream_t stream)
{
    const float* x         = (const float*)d_in[0];
    const float* rel_repr  = (const float*)d_in[1];
    const float* edge_norm = (const float*)d_in[2];
    const float* in_w      = (const float*)d_in[3];
    const float* out_w     = (const float*)d_in[4];
    const float* loop_w    = (const float*)d_in[5];
    const float* w_rel     = (const float*)d_in[6];
    const float* loop_rel  = (const float*)d_in[7];
    const float* bias      = (const float*)d_in[8];
    const float* bn_gamma  = (const float*)d_in[9];
    const float* bn_beta   = (const float*)d_in[10];
    const int* edge_type   = (const int*)d_in[11];
    const int* src         = (const int*)d_in[12];
    const int* dst         = (const int*)d_in[13];

    const int V = in_sizes[0] / 128;     // 50000
    const int E = in_sizes[2];           // 800000
    const int R = in_sizes[1] / 128;     // 200
    const int NK = 2 * V;                // keys: [dst(in) ; dst(out)]
    const int NBC = (NK + CB - 1) / CB;              // coarse buckets (782)
    const int NBLK = (E + CHUNK - 1) / CHUNK;        // hist/rank blocks (98)
    const int CN = NBC * NBLK;                       // scan length (76636)
    const int NB2 = (CN + SCAN_BLOCK - 1) / SCAN_BLOCK;  // scan blocks (<=1024)

    float* h       = (float*)d_out;              // [V,128]
    float* out_rel = h + (size_t)V * 128;        // [R,128]

    // workspace layout
    char* wp_ = (char*)d_ws;
    short* accbf   = (short*)wp_;  wp_ += (size_t)NK * 128 * sizeof(short);
    short* xbf     = (short*)wp_;  wp_ += (size_t)V * 128 * sizeof(short);
    short* relbf   = (short*)wp_;  wp_ += (size_t)R * 128 * sizeof(short);
    short* wpack   = (short*)wp_;  wp_ += (size_t)3 * 8 * 4 * 64 * 8 * sizeof(short);
    float* stats   = (float*)wp_;  wp_ += 256 * sizeof(float);
    int*   counts  = (int*)wp_;    wp_ += (size_t)CN * sizeof(int);
    int*   basep   = (int*)wp_;    wp_ += (size_t)CN * sizeof(int);
    int*   partials= (int*)wp_;    wp_ += 1024 * sizeof(int);
    wp_ = (char*)(((uintptr_t)wp_ + 15) & ~(uintptr_t)15);
    uint2* pay     = (uint2*)wp_;

    // only stats needs zeroing (counts/base/pay/accbf fully written)
    hipMemsetAsync(stats, 0, 256 * sizeof(float), stream);

    {
        size_t total = ((size_t)(V + R) * 128) / 8;
        xcast_kernel<<<(int)((total + 255) / 256), 256, 0, stream>>>(
            x, rel_repr, xbf, relbf, V, R);
    }
    wpack_kernel<<<(3 * 8 * 4 * 64 + 255) / 256, 256, 0, stream>>>(
        in_w, out_w, loop_w, loop_rel, wpack);

    hist_coarse_kernel<<<NBLK, 256, 0, stream>>>(dst, counts, E, V, NBC, NBLK);
    scan_partial_kernel<<<NB2, SCAN_BLOCK, 0, stream>>>(counts, partials, CN);
    scan_top_kernel<<<1, 1024, 0, stream>>>(partials, NB2);
    scan_final_kernel<<<NB2, SCAN_BLOCK, 0, stream>>>(counts, partials, basep, CN);
    rank_coarse_kernel<<<NBLK, 256, 0, stream>>>(
        dst, src, edge_type, edge_norm, basep, pay, E, V, NBC, NBLK);
    aggregate_coarse_kernel<<<NBC, 256, 0, stream>>>(
        xbf, relbf, pay, basep, accbf, E, NK, NBC, NBLK);

    fused_gemm_mfma_kernel<<<(V + 63) / 64, 256, 0, stream>>>(
        accbf, xbf, wpack, bias, h, stats, V);

    bn_apply_kernel<<<1024, 256, 0, stream>>>(h, stats, bn_gamma, bn_beta, V);
    rel_gemm_kernel<<<(R + 1) / 2, 256, 0, stream>>>(rel_repr, w_rel, out_rel, R);
}

// Round 8
// 216.689 us; speedup vs baseline: 3.7945x; 3.7945x over previous
//
#include <hip/hip_runtime.h>
#include <hip/hip_bf16.h>

// ---------------------------------------------------------------------------
// CompGCN layer:
//   bf16 data plane; coarse-bucket (128 keys) counting sort with low write
//   amplification; per-bucket LDS fine sort + register aggregation;
//   bf16-MFMA fused 3-way GEMM with BN-stats epilogue; BN apply + ReLU;
//   out_rel = rel @ w_rel.
// ---------------------------------------------------------------------------

#define SCAN_BLOCK 256
#define CB 128               // keys per coarse bucket
#define CHUNK 4096           // edges per hist/rank block
#define NBC_MAX 800          // >= ceil(2V/CB) = 782
#define CAP 3072             // max edges staged per bucket (lambda=1024, 64 sigma)

typedef __attribute__((ext_vector_type(8))) short short8v;   // 8 bf16
typedef __attribute__((ext_vector_type(4))) float float4v;   // MFMA C/D

__device__ inline short f2bf(float f) {
    union { float f; unsigned u; } c; c.f = f;
    unsigned u = c.u;
    return (short)((u + 0x7fffu + ((u >> 16) & 1u)) >> 16);  // RNE
}
__device__ inline float bflo(unsigned u) { return __uint_as_float(u << 16); }
__device__ inline float bfhi(unsigned u) { return __uint_as_float(u & 0xffff0000u); }

// cast x [V,128] and rel [R,128] to bf16, 8 elems/thread
__global__ __launch_bounds__(256) void xcast_kernel(
    const float* __restrict__ x, const float* __restrict__ rel,
    short* __restrict__ xbf, short* __restrict__ relbf, int V, int R)
{
    size_t i = ((size_t)blockIdx.x * 256 + threadIdx.x) * 8;
    size_t nx = (size_t)V * 128;
    size_t total = nx + (size_t)R * 128;
    if (i >= total) return;
    const float* sp; short* dp; size_t k;
    if (i < nx) { sp = x; dp = xbf; k = i; }
    else        { sp = rel; dp = relbf; k = i - nx; }
    float4 v0 = *reinterpret_cast<const float4*>(sp + k);
    float4 v1 = *reinterpret_cast<const float4*>(sp + k + 4);
    short8v o;
    o[0] = f2bf(v0.x); o[1] = f2bf(v0.y); o[2] = f2bf(v0.z); o[3] = f2bf(v0.w);
    o[4] = f2bf(v1.x); o[5] = f2bf(v1.y); o[6] = f2bf(v1.z); o[7] = f2bf(v1.w);
    *reinterpret_cast<short8v*>(dp + k) = o;
}

// per-block LDS histogram over coarse buckets; counts stored BLOCK-MAJOR
// (counts[blk*NBC + b]) so writes coalesce into full lines.
__global__ __launch_bounds__(256) void hist_coarse_kernel(
    const int* __restrict__ dst, int* __restrict__ counts,
    int E, int V, int NBC)
{
    __shared__ int lh[NBC_MAX];
    for (int i = threadIdx.x; i < NBC; i += 256) lh[i] = 0;
    __syncthreads();
    int half = E >> 1;
    int e0 = blockIdx.x * CHUNK;
    for (int i = 0; i < CHUNK / 256; ++i) {
        int e = e0 + i * 256 + threadIdx.x;
        if (e < E) {
            int key = dst[e] + (e < half ? 0 : V);
            atomicAdd(&lh[key >> 7], 1);
        }
    }
    __syncthreads();
    for (int i = threadIdx.x; i < NBC; i += 256)
        counts[(size_t)blockIdx.x * NBC + i] = lh[i];
}

// scan phase 1 with TRANSPOSED read: logical l = bucket*NBLK + blk,
// physical = blk*NBC + bucket (reads are L2/L3-hot, no write amp anywhere).
__global__ __launch_bounds__(SCAN_BLOCK) void scan_partial_t_kernel(
    const int* __restrict__ cnt_bm, int* __restrict__ partials,
    int CN, int NBC, int NBLK)
{
    __shared__ int red[SCAN_BLOCK];
    int l = blockIdx.x * SCAN_BLOCK + threadIdx.x;
    int v = 0;
    if (l < CN) {
        int bu = l / NBLK, bl = l - bu * NBLK;
        v = cnt_bm[(size_t)bl * NBC + bu];
    }
    red[threadIdx.x] = v;
    __syncthreads();
    for (int s = SCAN_BLOCK / 2; s > 0; s >>= 1) {
        if (threadIdx.x < s) red[threadIdx.x] += red[threadIdx.x + s];
        __syncthreads();
    }
    if (threadIdx.x == 0) partials[blockIdx.x] = red[0];
}

__global__ __launch_bounds__(1024) void scan_top_kernel(
    int* __restrict__ partials, int NB)
{
    __shared__ int sh[1024];
    int t = threadIdx.x;
    sh[t] = (t < NB) ? partials[t] : 0;
    __syncthreads();
    for (int s = 1; s < 1024; s <<= 1) {
        int v = (t >= s) ? sh[t - s] : 0;
        __syncthreads();
        sh[t] += v;
        __syncthreads();
    }
    if (t < NB) partials[t] = (t == 0) ? 0 : sh[t - 1];
}

// scan phase 3 (transposed read); base written bucket-major (coalesced).
__global__ __launch_bounds__(SCAN_BLOCK) void scan_final_t_kernel(
    const int* __restrict__ cnt_bm, const int* __restrict__ partials,
    int* __restrict__ base, int CN, int NBC, int NBLK)
{
    __shared__ int sh[SCAN_BLOCK];
    int l = blockIdx.x * SCAN_BLOCK + threadIdx.x;
    int t = threadIdx.x;
    int v = 0;
    if (l < CN) {
        int bu = l / NBLK, bl = l - bu * NBLK;
        v = cnt_bm[(size_t)bl * NBC + bu];
    }
    sh[t] = v;
    __syncthreads();
    for (int s = 1; s < SCAN_BLOCK; s <<= 1) {
        int u = (t >= s) ? sh[t - s] : 0;
        __syncthreads();
        sh[t] += u;
        __syncthreads();
    }
    if (l < CN) base[l] = partials[blockIdx.x] + sh[t] - v;
}

// scatter payload; per-(bucket,block) runs contiguous, written from one CU.
// payload: (src<<16 | type<<8 | key&127, norm-bits)
__global__ __launch_bounds__(256) void rank_coarse_kernel(
    const int* __restrict__ dst,
    const int* __restrict__ src,
    const int* __restrict__ edge_type,
    const float* __restrict__ edge_norm,
    const int* __restrict__ base,
    uint2* __restrict__ pay,
    int E, int V, int NBC, int NBLK)
{
    __shared__ int lh[NBC_MAX];   // running intra-run rank
    __shared__ int lb[NBC_MAX];   // this block's run base per bucket
    for (int i = threadIdx.x; i < NBC; i += 256) {
        lh[i] = 0;
        lb[i] = base[(size_t)i * NBLK + blockIdx.x];
    }
    __syncthreads();
    int half = E >> 1;
    int e0 = blockIdx.x * CHUNK;
    for (int i = 0; i < CHUNK / 256; ++i) {
        int e = e0 + i * 256 + threadIdx.x;
        if (e < E) {
            int d = dst[e], s = src[e], t = edge_type[e];
            float n = edge_norm[e];
            int key = d + (e < half ? 0 : V);
            int b = key >> 7;
            int r = atomicAdd(&lh[b], 1);
            pay[lb[b] + r] = make_uint2(
                ((unsigned)s << 16) | ((unsigned)t << 8) | (unsigned)(key & 127),
                __float_as_uint(n));
        }
    }
}

// one block per coarse bucket: counting-sort the bucket's payload into LDS,
// then 8x32-lane groups accumulate per key in registers (round-5 structure).
__global__ __launch_bounds__(256) void aggregate_fine_kernel(
    const short* __restrict__ xbf,
    const short* __restrict__ relbf,
    const uint2* __restrict__ pay,
    const int* __restrict__ base,
    short* __restrict__ accbf,       // [NK,128]
    int E, int NK, int NBC, int NBLK)
{
    __shared__ uint2 pay_s[CAP];     // 24 KB
    __shared__ int fcnt[CB];
    __shared__ int foff[CB + 1];
    __shared__ int fcur[CB];
    __shared__ int ssc[CB];

    int b = blockIdx.x;
    int beg = base[(size_t)b * NBLK];
    int end = (b + 1 < NBC) ? base[(size_t)(b + 1) * NBLK] : E;
    int cnt = end - beg;
    int tid = threadIdx.x;
    int g = tid >> 5, lane = tid & 31, f0 = lane << 2;

    if (cnt <= CAP) {
        if (tid < CB) fcnt[tid] = 0;
        __syncthreads();
        // pass 1: count fine keys (coalesced payload read)
        for (int j = tid; j < cnt; j += 256)
            atomicAdd(&fcnt[pay[beg + j].x & 127u], 1);
        __syncthreads();
        // inclusive scan of fcnt (128 entries)
        if (tid < CB) ssc[tid] = fcnt[tid];
        __syncthreads();
        for (int s = 1; s < CB; s <<= 1) {
            int v = 0;
            if (tid < CB && tid >= s) v = ssc[tid - s];
            __syncthreads();
            if (tid < CB) ssc[tid] += v;
            __syncthreads();
        }
        if (tid < CB) { foff[tid + 1] = ssc[tid]; fcur[tid] = ssc[tid] - fcnt[tid]; }
        if (tid == 0) foff[0] = 0;
        __syncthreads();
        // pass 2: scatter into sorted LDS staging
        for (int j = tid; j < cnt; j += 256) {
            uint2 p = pay[beg + j];
            int r = atomicAdd(&fcur[p.x & 127u], 1);
            pay_s[r] = p;
        }
        __syncthreads();
        // per-key register aggregation; group g owns keys g, g+8, ...
        for (int k = g; k < CB; k += 8) {
            int key = b * CB + k;
            if (key >= NK) continue;
            float a0 = 0.f, a1 = 0.f, a2 = 0.f, a3 = 0.f;
            int p0 = foff[k], p1 = foff[k + 1];
            for (int pos = p0; pos < p1; ++pos) {
                uint2 p = pay_s[pos];                    // LDS broadcast
                float nq = __uint_as_float(p.y);
                int s = (int)(p.x >> 16);
                int t = (int)((p.x >> 8) & 0xffu);
                uint2 xv = *reinterpret_cast<const uint2*>(xbf + (size_t)s * 128 + f0);
                uint2 rv = *reinterpret_cast<const uint2*>(relbf + (size_t)t * 128 + f0);
                a0 += bflo(xv.x) * bflo(rv.x) * nq;
                a1 += bfhi(xv.x) * bfhi(rv.x) * nq;
                a2 += bflo(xv.y) * bflo(rv.y) * nq;
                a3 += bfhi(xv.y) * bfhi(rv.y) * nq;
            }
            uint2 o;
            o.x = (unsigned)(unsigned short)f2bf(a0) | ((unsigned)(unsigned short)f2bf(a1) << 16);
            o.y = (unsigned)(unsigned short)f2bf(a2) | ((unsigned)(unsigned short)f2bf(a3) << 16);
            *reinterpret_cast<uint2*>(accbf + (size_t)key * 128 + f0) = o;
        }
    } else {
        // correctness fallback (never taken for uniform inputs): direct scan
        for (int k = g; k < CB; k += 8) {
            int key = b * CB + k;
            if (key >= NK) continue;
            float a0 = 0.f, a1 = 0.f, a2 = 0.f, a3 = 0.f;
            for (int j = beg; j < end; ++j) {
                uint2 p = pay[j];
                if ((int)(p.x & 127u) != k) continue;
                float nq = __uint_as_float(p.y);
                int s = (int)(p.x >> 16);
                int t = (int)((p.x >> 8) & 0xffu);
                uint2 xv = *reinterpret_cast<const uint2*>(xbf + (size_t)s * 128 + f0);
                uint2 rv = *reinterpret_cast<const uint2*>(relbf + (size_t)t * 128 + f0);
                a0 += bflo(xv.x) * bflo(rv.x) * nq;
                a1 += bfhi(xv.x) * bfhi(rv.x) * nq;
                a2 += bflo(xv.y) * bflo(rv.y) * nq;
                a3 += bfhi(xv.y) * bfhi(rv.y) * nq;
            }
            uint2 o;
            o.x = (unsigned)(unsigned short)f2bf(a0) | ((unsigned)(unsigned short)f2bf(a1) << 16);
            o.y = (unsigned)(unsigned short)f2bf(a2) | ((unsigned)(unsigned short)f2bf(a3) << 16);
            *reinterpret_cast<uint2*>(accbf + (size_t)key * 128 + f0) = o;
        }
    }
}

// pack weights into bf16 MFMA B-fragment order; loop_rel folded into loop_w
__global__ __launch_bounds__(256) void wpack_kernel(
    const float* __restrict__ in_w,
    const float* __restrict__ out_w,
    const float* __restrict__ loop_w,
    const float* __restrict__ loop_rel,
    short* __restrict__ wpack)
{
    int idx = blockIdx.x * 256 + threadIdx.x;
    if (idx >= 3 * 8 * 4 * 64) return;
    int lane = idx & 63;
    int t    = (idx >> 6) & 3;
    int cblk = (idx >> 8) & 7;
    int m    = idx >> 11;
    const float* W = (m == 0) ? in_w : (m == 1) ? out_w : loop_w;
    int col = cblk * 16 + (lane & 15);
    int kb  = t * 32 + ((lane >> 4) << 3);
    short8v v;
#pragma unroll
    for (int j = 0; j < 8; ++j) {
        float w = W[(kb + j) * 128 + col];
        if (m == 2) w *= loop_rel[kb + j];
        v[j] = f2bf(w);
    }
    *reinterpret_cast<short8v*>(wpack + (size_t)idx * 8) = v;
}

// bf16 MFMA fused GEMM + bias + /3, BN stats fused into epilogue
__global__ __launch_bounds__(256) void fused_gemm_mfma_kernel(
    const short* __restrict__ accbf,     // [2V,128]
    const short* __restrict__ xbf,       // [V,128]
    const short* __restrict__ wpack,
    const float* __restrict__ bias,
    float* __restrict__ h,
    float* __restrict__ stats,           // [0:128] sum, [128:256] sumsq
    int V)
{
    __shared__ float s_red[256];

    int wave = threadIdx.x >> 6;
    int lane = threadIdx.x & 63;
    int kgrp = lane >> 4;
    int row0 = blockIdx.x * 64 + wave * 16;
    int rowl = row0 + (lane & 15);
    int rowc = min(rowl, V - 1);          // clamp (stores guarded)

    for (int i = threadIdx.x; i < 256; i += 256) s_red[i] = 0.f;

    float4v c[8];
#pragma unroll
    for (int b = 0; b < 8; ++b) c[b] = (float4v)(0.f);

    const short* mats[3] = { accbf, accbf + (size_t)V * 128, xbf };

    for (int m = 0; m < 3; ++m) {
        const short* A = mats[m] + (size_t)rowc * 128;
#pragma unroll
        for (int t = 0; t < 4; ++t) {
            short8v af = *reinterpret_cast<const short8v*>(A + t * 32 + (kgrp << 3));
            const short* wp = wpack + (((size_t)(m * 8) * 4 + t) * 64 + lane) * 8;
#pragma unroll
            for (int b = 0; b < 8; ++b) {
                short8v bf_ = *reinterpret_cast<const short8v*>(wp + (size_t)b * 4 * 64 * 8);
                c[b] = __builtin_amdgcn_mfma_f32_16x16x32_bf16(af, bf_, c[b], 0, 0, 0);
            }
        }
    }
    __syncthreads();   // s_red zeroed

    // epilogue: C/D layout col=lane&15, row=(lane>>4)*4+r  [m89]
#pragma unroll
    for (int b = 0; b < 8; ++b) {
        int col = b * 16 + (lane & 15);
        float bv = bias[col];
        float ps = 0.f, pq = 0.f;
#pragma unroll
        for (int r = 0; r < 4; ++r) {
            int row = row0 + kgrp * 4 + r;
            if (row < V) {
                float v = c[b][r] * (1.f / 3.f) + bv;
                h[(size_t)row * 128 + col] = v;
                ps += v;
                pq += v * v;
            }
        }
        atomicAdd(&s_red[col], ps);
        atomicAdd(&s_red[128 + col], pq);
    }
    __syncthreads();
    if (threadIdx.x < 256)
        atomicAdd(&stats[threadIdx.x], s_red[threadIdx.x]);
}

__global__ __launch_bounds__(256) void bn_apply_kernel(
    float* __restrict__ h,
    const float* __restrict__ stats,
    const float* __restrict__ gamma,
    const float* __restrict__ beta,
    int V)
{
    int col = threadIdx.x & 127;
    int rg  = threadIdx.x >> 7;
    float inv_v = 1.f / (float)V;
    float mean = stats[col] * inv_v;
    float var  = stats[128 + col] * inv_v - mean * mean;
    float sc = rsqrtf(var + 1e-5f) * gamma[col];
    float sh = beta[col] - mean * sc;
    for (int row = blockIdx.x * 2 + rg; row < V; row += gridDim.x * 2) {
        float v = h[(size_t)row * 128 + col];
        v = v * sc + sh;
        h[(size_t)row * 128 + col] = v > 0.f ? v : 0.f;
    }
}

__global__ __launch_bounds__(256) void rel_gemm_kernel(
    const float* __restrict__ rel,
    const float* __restrict__ w_rel,
    float* __restrict__ out_rel,
    int R)
{
    int col = threadIdx.x & 127;
    int row = blockIdx.x * 2 + (threadIdx.x >> 7);
    if (row >= R) return;
    float acc = 0.f;
    for (int k = 0; k < 128; ++k)
        acc += rel[row * 128 + k] * w_rel[k * 128 + col];
    out_rel[row * 128 + col] = acc;
}

extern "C" void kernel_launch(void* const* d_in, const int* in_sizes, int n_in,
                              void* d_out, int out_size, void* d_ws, size_t ws_size,
                              hipStream_t stream)
{
    const float* x         = (const float*)d_in[0];
    const float* rel_repr  = (const float*)d_in[1];
    const float* edge_norm = (const float*)d_in[2];
    const float* in_w      = (const float*)d_in[3];
    const float* out_w     = (const float*)d_in[4];
    const float* loop_w    = (const float*)d_in[5];
    const float* w_rel     = (const float*)d_in[6];
    const float* loop_rel  = (const float*)d_in[7];
    const float* bias      = (const float*)d_in[8];
    const float* bn_gamma  = (const float*)d_in[9];
    const float* bn_beta   = (const float*)d_in[10];
    const int* edge_type   = (const int*)d_in[11];
    const int* src         = (const int*)d_in[12];
    const int* dst         = (const int*)d_in[13];

    const int V = in_sizes[0] / 128;     // 50000
    const int E = in_sizes[2];           // 800000
    const int R = in_sizes[1] / 128;     // 200
    const int NK = 2 * V;                // keys: [dst(in) ; dst(out)]
    const int NBC = (NK + CB - 1) / CB;              // coarse buckets (782)
    const int NBLK = (E + CHUNK - 1) / CHUNK;        // hist/rank blocks (196)
    const int CN = NBC * NBLK;                       // scan length (153272)
    const int NB2 = (CN + SCAN_BLOCK - 1) / SCAN_BLOCK;  // scan blocks (599)

    float* h       = (float*)d_out;              // [V,128]
    float* out_rel = h + (size_t)V * 128;        // [R,128]

    // workspace layout
    char* wp_ = (char*)d_ws;
    short* accbf   = (short*)wp_;  wp_ += (size_t)NK * 128 * sizeof(short);
    short* xbf     = (short*)wp_;  wp_ += (size_t)V * 128 * sizeof(short);
    short* relbf   = (short*)wp_;  wp_ += (size_t)R * 128 * sizeof(short);
    short* wpack   = (short*)wp_;  wp_ += (size_t)3 * 8 * 4 * 64 * 8 * sizeof(short);
    float* stats   = (float*)wp_;  wp_ += 256 * sizeof(float);
    int*   counts  = (int*)wp_;    wp_ += (size_t)CN * sizeof(int);   // block-major
    int*   basep   = (int*)wp_;    wp_ += (size_t)CN * sizeof(int);   // bucket-major
    int*   partials= (int*)wp_;    wp_ += 1024 * sizeof(int);
    wp_ = (char*)(((uintptr_t)wp_ + 15) & ~(uintptr_t)15);
    uint2* pay     = (uint2*)wp_;

    // only stats needs zeroing (counts/basep/pay/accbf fully written)
    hipMemsetAsync(stats, 0, 256 * sizeof(float), stream);

    {
        size_t total = ((size_t)(V + R) * 128) / 8;
        xcast_kernel<<<(int)((total + 255) / 256), 256, 0, stream>>>(
            x, rel_repr, xbf, relbf, V, R);
    }
    wpack_kernel<<<(3 * 8 * 4 * 64 + 255) / 256, 256, 0, stream>>>(
        in_w, out_w, loop_w, loop_rel, wpack);

    hist_coarse_kernel<<<NBLK, 256, 0, stream>>>(dst, counts, E, V, NBC);
    scan_partial_t_kernel<<<NB2, SCAN_BLOCK, 0, stream>>>(counts, partials, CN, NBC, NBLK);
    scan_top_kernel<<<1, 1024, 0, stream>>>(partials, NB2);
    scan_final_t_kernel<<<NB2, SCAN_BLOCK, 0, stream>>>(counts, partials, basep, CN, NBC, NBLK);
    rank_coarse_kernel<<<NBLK, 256, 0, stream>>>(
        dst, src, edge_type, edge_norm, basep, pay, E, V, NBC, NBLK);
    aggregate_fine_kernel<<<NBC, 256, 0, stream>>>(
        xbf, relbf, pay, basep, accbf, E, NK, NBC, NBLK);

    fused_gemm_mfma_kernel<<<(V + 63) / 64, 256, 0, stream>>>(
        accbf, xbf, wpack, bias, h, stats, V);

    bn_apply_kernel<<<1024, 256, 0, stream>>>(h, stats, bn_gamma, bn_beta, V);
    rel_gemm_kernel<<<(R + 1) / 2, 256, 0, stream>>>(rel_repr, w_rel, out_rel, R);
}

// Round 9
// 161.511 us; speedup vs baseline: 5.0909x; 1.3416x over previous
//
#include <hip/hip_runtime.h>
#include <hip/hip_bf16.h>

// ---------------------------------------------------------------------------
// CompGCN layer:
//   bf16 data plane; coarse-bucket (128 keys) counting sort (low write amp);
//   per-bucket LDS fine sort -> key-sorted payload + per-key CSR;
//   per-key 32-lane register aggregation (high occupancy);
//   bf16-MFMA fused 3-way GEMM with BN-stats epilogue; BN apply + ReLU;
//   out_rel = rel @ w_rel.
// ---------------------------------------------------------------------------

#define SCAN_BLOCK 256
#define CB 128               // keys per coarse bucket
#define CHUNK 4096           // edges per hist/rank block
#define NBC_MAX 800          // >= ceil(2V/CB) = 782
#define CAP 3072             // LDS staging cap per bucket (lambda=1024, 64 sigma)

typedef __attribute__((ext_vector_type(8))) short short8v;   // 8 bf16
typedef __attribute__((ext_vector_type(4))) float float4v;   // MFMA C/D

__device__ inline short f2bf(float f) {
    union { float f; unsigned u; } c; c.f = f;
    unsigned u = c.u;
    return (short)((u + 0x7fffu + ((u >> 16) & 1u)) >> 16);  // RNE
}
__device__ inline float bflo(unsigned u) { return __uint_as_float(u << 16); }
__device__ inline float bfhi(unsigned u) { return __uint_as_float(u & 0xffff0000u); }

// cast x [V,128] and rel [R,128] to bf16, 8 elems/thread
__global__ __launch_bounds__(256) void xcast_kernel(
    const float* __restrict__ x, const float* __restrict__ rel,
    short* __restrict__ xbf, short* __restrict__ relbf, int V, int R)
{
    size_t i = ((size_t)blockIdx.x * 256 + threadIdx.x) * 8;
    size_t nx = (size_t)V * 128;
    size_t total = nx + (size_t)R * 128;
    if (i >= total) return;
    const float* sp; short* dp; size_t k;
    if (i < nx) { sp = x; dp = xbf; k = i; }
    else        { sp = rel; dp = relbf; k = i - nx; }
    float4 v0 = *reinterpret_cast<const float4*>(sp + k);
    float4 v1 = *reinterpret_cast<const float4*>(sp + k + 4);
    short8v o;
    o[0] = f2bf(v0.x); o[1] = f2bf(v0.y); o[2] = f2bf(v0.z); o[3] = f2bf(v0.w);
    o[4] = f2bf(v1.x); o[5] = f2bf(v1.y); o[6] = f2bf(v1.z); o[7] = f2bf(v1.w);
    *reinterpret_cast<short8v*>(dp + k) = o;
}

// per-block LDS histogram over coarse buckets; counts stored BLOCK-MAJOR
__global__ __launch_bounds__(256) void hist_coarse_kernel(
    const int* __restrict__ dst, int* __restrict__ counts,
    int E, int V, int NBC)
{
    __shared__ int lh[NBC_MAX];
    for (int i = threadIdx.x; i < NBC; i += 256) lh[i] = 0;
    __syncthreads();
    int half = E >> 1;
    int e0 = blockIdx.x * CHUNK;
    for (int i = 0; i < CHUNK / 256; ++i) {
        int e = e0 + i * 256 + threadIdx.x;
        if (e < E) {
            int key = dst[e] + (e < half ? 0 : V);
            atomicAdd(&lh[key >> 7], 1);
        }
    }
    __syncthreads();
    for (int i = threadIdx.x; i < NBC; i += 256)
        counts[(size_t)blockIdx.x * NBC + i] = lh[i];
}

// scan phase 1, TRANSPOSED read: logical l = bucket*NBLK + blk
__global__ __launch_bounds__(SCAN_BLOCK) void scan_partial_t_kernel(
    const int* __restrict__ cnt_bm, int* __restrict__ partials,
    int CN, int NBC, int NBLK)
{
    __shared__ int red[SCAN_BLOCK];
    int l = blockIdx.x * SCAN_BLOCK + threadIdx.x;
    int v = 0;
    if (l < CN) {
        int bu = l / NBLK, bl = l - bu * NBLK;
        v = cnt_bm[(size_t)bl * NBC + bu];
    }
    red[threadIdx.x] = v;
    __syncthreads();
    for (int s = SCAN_BLOCK / 2; s > 0; s >>= 1) {
        if (threadIdx.x < s) red[threadIdx.x] += red[threadIdx.x + s];
        __syncthreads();
    }
    if (threadIdx.x == 0) partials[blockIdx.x] = red[0];
}

__global__ __launch_bounds__(1024) void scan_top_kernel(
    int* __restrict__ partials, int NB)
{
    __shared__ int sh[1024];
    int t = threadIdx.x;
    sh[t] = (t < NB) ? partials[t] : 0;
    __syncthreads();
    for (int s = 1; s < 1024; s <<= 1) {
        int v = (t >= s) ? sh[t - s] : 0;
        __syncthreads();
        sh[t] += v;
        __syncthreads();
    }
    if (t < NB) partials[t] = (t == 0) ? 0 : sh[t - 1];
}

__global__ __launch_bounds__(SCAN_BLOCK) void scan_final_t_kernel(
    const int* __restrict__ cnt_bm, const int* __restrict__ partials,
    int* __restrict__ base, int CN, int NBC, int NBLK)
{
    __shared__ int sh[SCAN_BLOCK];
    int l = blockIdx.x * SCAN_BLOCK + threadIdx.x;
    int t = threadIdx.x;
    int v = 0;
    if (l < CN) {
        int bu = l / NBLK, bl = l - bu * NBLK;
        v = cnt_bm[(size_t)bl * NBC + bu];
    }
    sh[t] = v;
    __syncthreads();
    for (int s = 1; s < SCAN_BLOCK; s <<= 1) {
        int u = (t >= s) ? sh[t - s] : 0;
        __syncthreads();
        sh[t] += u;
        __syncthreads();
    }
    if (l < CN) base[l] = partials[blockIdx.x] + sh[t] - v;
}

// scatter payload; per-(bucket,block) runs contiguous, written from one CU.
// payload: (src<<16 | type<<8 | key&127, norm-bits)
__global__ __launch_bounds__(256) void rank_coarse_kernel(
    const int* __restrict__ dst,
    const int* __restrict__ src,
    const int* __restrict__ edge_type,
    const float* __restrict__ edge_norm,
    const int* __restrict__ base,
    uint2* __restrict__ pay,
    int E, int V, int NBC, int NBLK)
{
    __shared__ int lh[NBC_MAX];
    __shared__ int lb[NBC_MAX];
    for (int i = threadIdx.x; i < NBC; i += 256) {
        lh[i] = 0;
        lb[i] = base[(size_t)i * NBLK + blockIdx.x];
    }
    __syncthreads();
    int half = E >> 1;
    int e0 = blockIdx.x * CHUNK;
    for (int i = 0; i < CHUNK / 256; ++i) {
        int e = e0 + i * 256 + threadIdx.x;
        if (e < E) {
            int d = dst[e], s = src[e], t = edge_type[e];
            float n = edge_norm[e];
            int key = d + (e < half ? 0 : V);
            int b = key >> 7;
            int r = atomicAdd(&lh[b], 1);
            pay[lb[b] + r] = make_uint2(
                ((unsigned)s << 16) | ((unsigned)t << 8) | (unsigned)(key & 127),
                __float_as_uint(n));
        }
    }
}

// one block per coarse bucket: LDS counting sort of the bucket's payload;
// writes key-sorted pay2 (coalesced) + per-key CSR foffg [NK+1].
__global__ __launch_bounds__(256) void fine_sort_kernel(
    const uint2* __restrict__ pay,
    const int* __restrict__ base,
    uint2* __restrict__ pay2,
    int* __restrict__ foffg,
    int E, int NK, int NBC, int NBLK)
{
    __shared__ uint2 pay_s[CAP];     // 24 KB
    __shared__ int fcnt[CB];
    __shared__ int ssc[CB];
    __shared__ int fcur[CB];
    __shared__ int foff[CB];

    int b = blockIdx.x;
    int beg = base[(size_t)b * NBLK];
    int end = (b + 1 < NBC) ? base[(size_t)(b + 1) * NBLK] : E;
    int cnt = end - beg;
    int tid = threadIdx.x;

    if (tid < CB) fcnt[tid] = 0;
    __syncthreads();
    // pass 1: count fine keys (coalesced payload read)
    for (int j = tid; j < cnt; j += 256)
        atomicAdd(&fcnt[pay[beg + j].x & 127u], 1);
    __syncthreads();
    // inclusive scan of fcnt
    if (tid < CB) ssc[tid] = fcnt[tid];
    __syncthreads();
    for (int s = 1; s < CB; s <<= 1) {
        int v = 0;
        if (tid < CB && tid >= s) v = ssc[tid - s];
        __syncthreads();
        if (tid < CB) ssc[tid] += v;
        __syncthreads();
    }
    if (tid < CB) {
        int ex = ssc[tid] - fcnt[tid];
        foff[tid] = ex;
        fcur[tid] = ex;
        int key = b * CB + tid;
        if (key <= NK) foffg[key] = beg + ex;
    }
    __syncthreads();

    if (cnt <= CAP) {
        // scatter into LDS staging, then coalesced writeback
        for (int j = tid; j < cnt; j += 256) {
            uint2 p = pay[beg + j];
            int r = atomicAdd(&fcur[p.x & 127u], 1);
            pay_s[r] = p;
        }
        __syncthreads();
        for (int j = tid; j < cnt; j += 256) pay2[beg + j] = pay_s[j];
    } else {
        // fallback (never taken for uniform inputs): direct global scatter
        for (int j = tid; j < cnt; j += 256) {
            uint2 p = pay[beg + j];
            int r = atomicAdd(&fcur[p.x & 127u], 1);
            pay2[beg + r] = p;
        }
    }
}

// one 32-lane group per key; contiguous payload, register accumulation
__global__ __launch_bounds__(256) void aggregate_csr_kernel(
    const short* __restrict__ xbf,
    const short* __restrict__ relbf,
    const uint2* __restrict__ pay2,
    const int* __restrict__ foffg,
    short* __restrict__ accbf,       // [NK,128]
    int NK)
{
    int gid = (blockIdx.x * 256 + threadIdx.x) >> 5;
    if (gid >= NK) return;
    int lane = threadIdx.x & 31;
    int f0 = lane << 2;

    int beg = foffg[gid], end = foffg[gid + 1];
    float a0 = 0.f, a1 = 0.f, a2 = 0.f, a3 = 0.f;

    for (int bas = beg; bas < end; bas += 32) {
        int j = bas + lane;
        uint2 p = (j < end) ? pay2[j] : make_uint2(0u, 0u);
        int m = min(32, end - bas);
        for (int q = 0; q < m; ++q) {
            unsigned pq = __shfl(p.x, q, 32);
            float nq = __uint_as_float(__shfl(p.y, q, 32));
            int s = (int)(pq >> 16);
            int t = (int)((pq >> 8) & 0xffu);
            uint2 xv = *reinterpret_cast<const uint2*>(xbf + (size_t)s * 128 + f0);
            uint2 rv = *reinterpret_cast<const uint2*>(relbf + (size_t)t * 128 + f0);
            a0 += bflo(xv.x) * bflo(rv.x) * nq;
            a1 += bfhi(xv.x) * bfhi(rv.x) * nq;
            a2 += bflo(xv.y) * bflo(rv.y) * nq;
            a3 += bfhi(xv.y) * bfhi(rv.y) * nq;
        }
    }
    uint2 o;
    o.x = (unsigned)(unsigned short)f2bf(a0) | ((unsigned)(unsigned short)f2bf(a1) << 16);
    o.y = (unsigned)(unsigned short)f2bf(a2) | ((unsigned)(unsigned short)f2bf(a3) << 16);
    *reinterpret_cast<uint2*>(accbf + (size_t)gid * 128 + f0) = o;
}

// pack weights into bf16 MFMA B-fragment order; loop_rel folded into loop_w
__global__ __launch_bounds__(256) void wpack_kernel(
    const float* __restrict__ in_w,
    const float* __restrict__ out_w,
    const float* __restrict__ loop_w,
    const float* __restrict__ loop_rel,
    short* __restrict__ wpack)
{
    int idx = blockIdx.x * 256 + threadIdx.x;
    if (idx >= 3 * 8 * 4 * 64) return;
    int lane = idx & 63;
    int t    = (idx >> 6) & 3;
    int cblk = (idx >> 8) & 7;
    int m    = idx >> 11;
    const float* W = (m == 0) ? in_w : (m == 1) ? out_w : loop_w;
    int col = cblk * 16 + (lane & 15);
    int kb  = t * 32 + ((lane >> 4) << 3);
    short8v v;
#pragma unroll
    for (int j = 0; j < 8; ++j) {
        float w = W[(kb + j) * 128 + col];
        if (m == 2) w *= loop_rel[kb + j];
        v[j] = f2bf(w);
    }
    *reinterpret_cast<short8v*>(wpack + (size_t)idx * 8) = v;
}

// bf16 MFMA fused GEMM + bias + /3, BN stats fused into epilogue
__global__ __launch_bounds__(256) void fused_gemm_mfma_kernel(
    const short* __restrict__ accbf,     // [2V,128]
    const short* __restrict__ xbf,       // [V,128]
    const short* __restrict__ wpack,
    const float* __restrict__ bias,
    float* __restrict__ h,
    float* __restrict__ stats,           // [0:128] sum, [128:256] sumsq
    int V)
{
    __shared__ float s_red[256];

    int wave = threadIdx.x >> 6;
    int lane = threadIdx.x & 63;
    int kgrp = lane >> 4;
    int row0 = blockIdx.x * 64 + wave * 16;
    int rowl = row0 + (lane & 15);
    int rowc = min(rowl, V - 1);          // clamp (stores guarded)

    for (int i = threadIdx.x; i < 256; i += 256) s_red[i] = 0.f;

    float4v c[8];
#pragma unroll
    for (int b = 0; b < 8; ++b) c[b] = (float4v)(0.f);

    const short* mats[3] = { accbf, accbf + (size_t)V * 128, xbf };

    for (int m = 0; m < 3; ++m) {
        const short* A = mats[m] + (size_t)rowc * 128;
#pragma unroll
        for (int t = 0; t < 4; ++t) {
            short8v af = *reinterpret_cast<const short8v*>(A + t * 32 + (kgrp << 3));
            const short* wp = wpack + (((size_t)(m * 8) * 4 + t) * 64 + lane) * 8;
#pragma unroll
            for (int b = 0; b < 8; ++b) {
                short8v bf_ = *reinterpret_cast<const short8v*>(wp + (size_t)b * 4 * 64 * 8);
                c[b] = __builtin_amdgcn_mfma_f32_16x16x32_bf16(af, bf_, c[b], 0, 0, 0);
            }
        }
    }
    __syncthreads();   // s_red zeroed

    // epilogue: C/D layout col=lane&15, row=(lane>>4)*4+r  [m89]
#pragma unroll
    for (int b = 0; b < 8; ++b) {
        int col = b * 16 + (lane & 15);
        float bv = bias[col];
        float ps = 0.f, pq = 0.f;
#pragma unroll
        for (int r = 0; r < 4; ++r) {
            int row = row0 + kgrp * 4 + r;
            if (row < V) {
                float v = c[b][r] * (1.f / 3.f) + bv;
                h[(size_t)row * 128 + col] = v;
                ps += v;
                pq += v * v;
            }
        }
        atomicAdd(&s_red[col], ps);
        atomicAdd(&s_red[128 + col], pq);
    }
    __syncthreads();
    if (threadIdx.x < 256)
        atomicAdd(&stats[threadIdx.x], s_red[threadIdx.x]);
}

__global__ __launch_bounds__(256) void bn_apply_kernel(
    float* __restrict__ h,
    const float* __restrict__ stats,
    const float* __restrict__ gamma,
    const float* __restrict__ beta,
    int V)
{
    int col = threadIdx.x & 127;
    int rg  = threadIdx.x >> 7;
    float inv_v = 1.f / (float)V;
    float mean = stats[col] * inv_v;
    float var  = stats[128 + col] * inv_v - mean * mean;
    float sc = rsqrtf(var + 1e-5f) * gamma[col];
    float sh = beta[col] - mean * sc;
    for (int row = blockIdx.x * 2 + rg; row < V; row += gridDim.x * 2) {
        float v = h[(size_t)row * 128 + col];
        v = v * sc + sh;
        h[(size_t)row * 128 + col] = v > 0.f ? v : 0.f;
    }
}

__global__ __launch_bounds__(256) void rel_gemm_kernel(
    const float* __restrict__ rel,
    const float* __restrict__ w_rel,
    float* __restrict__ out_rel,
    int R)
{
    int col = threadIdx.x & 127;
    int row = blockIdx.x * 2 + (threadIdx.x >> 7);
    if (row >= R) return;
    float acc = 0.f;
    for (int k = 0; k < 128; ++k)
        acc += rel[row * 128 + k] * w_rel[k * 128 + col];
    out_rel[row * 128 + col] = acc;
}

extern "C" void kernel_launch(void* const* d_in, const int* in_sizes, int n_in,
                              void* d_out, int out_size, void* d_ws, size_t ws_size,
                              hipStream_t stream)
{
    const float* x         = (const float*)d_in[0];
    const float* rel_repr  = (const float*)d_in[1];
    const float* edge_norm = (const float*)d_in[2];
    const float* in_w      = (const float*)d_in[3];
    const float* out_w     = (const float*)d_in[4];
    const float* loop_w    = (const float*)d_in[5];
    const float* w_rel     = (const float*)d_in[6];
    const float* loop_rel  = (const float*)d_in[7];
    const float* bias      = (const float*)d_in[8];
    const float* bn_gamma  = (const float*)d_in[9];
    const float* bn_beta   = (const float*)d_in[10];
    const int* edge_type   = (const int*)d_in[11];
    const int* src         = (const int*)d_in[12];
    const int* dst         = (const int*)d_in[13];

    const int V = in_sizes[0] / 128;     // 50000
    const int E = in_sizes[2];           // 800000
    const int R = in_sizes[1] / 128;     // 200
    const int NK = 2 * V;                // keys: [dst(in) ; dst(out)]
    const int NBC = (NK + CB - 1) / CB;              // coarse buckets (782)
    const int NBLK = (E + CHUNK - 1) / CHUNK;        // hist/rank blocks (196)
    const int CN = NBC * NBLK;                       // scan length
    const int NB2 = (CN + SCAN_BLOCK - 1) / SCAN_BLOCK;

    float* h       = (float*)d_out;              // [V,128]
    float* out_rel = h + (size_t)V * 128;        // [R,128]

    // workspace layout
    char* wp_ = (char*)d_ws;
    short* accbf   = (short*)wp_;  wp_ += (size_t)NK * 128 * sizeof(short);
    short* xbf     = (short*)wp_;  wp_ += (size_t)V * 128 * sizeof(short);
    short* relbf   = (short*)wp_;  wp_ += (size_t)R * 128 * sizeof(short);
    short* wpack   = (short*)wp_;  wp_ += (size_t)3 * 8 * 4 * 64 * 8 * sizeof(short);
    float* stats   = (float*)wp_;  wp_ += 256 * sizeof(float);
    int*   counts  = (int*)wp_;    wp_ += (size_t)CN * sizeof(int);   // block-major
    int*   basep   = (int*)wp_;    wp_ += (size_t)CN * sizeof(int);   // bucket-major
    int*   partials= (int*)wp_;    wp_ += 1024 * sizeof(int);
    int*   foffg   = (int*)wp_;    wp_ += ((size_t)NK + 2) * sizeof(int);
    wp_ = (char*)(((uintptr_t)wp_ + 15) & ~(uintptr_t)15);
    uint2* pay     = (uint2*)wp_;  wp_ += (size_t)E * sizeof(uint2);
    uint2* pay2    = (uint2*)wp_;

    // only stats needs zeroing
    hipMemsetAsync(stats, 0, 256 * sizeof(float), stream);

    {
        size_t total = ((size_t)(V + R) * 128) / 8;
        xcast_kernel<<<(int)((total + 255) / 256), 256, 0, stream>>>(
            x, rel_repr, xbf, relbf, V, R);
    }
    wpack_kernel<<<(3 * 8 * 4 * 64 + 255) / 256, 256, 0, stream>>>(
        in_w, out_w, loop_w, loop_rel, wpack);

    hist_coarse_kernel<<<NBLK, 256, 0, stream>>>(dst, counts, E, V, NBC);
    scan_partial_t_kernel<<<NB2, SCAN_BLOCK, 0, stream>>>(counts, partials, CN, NBC, NBLK);
    scan_top_kernel<<<1, 1024, 0, stream>>>(partials, NB2);
    scan_final_t_kernel<<<NB2, SCAN_BLOCK, 0, stream>>>(counts, partials, basep, CN, NBC, NBLK);
    rank_coarse_kernel<<<NBLK, 256, 0, stream>>>(
        dst, src, edge_type, edge_norm, basep, pay, E, V, NBC, NBLK);
    fine_sort_kernel<<<NBC, 256, 0, stream>>>(
        pay, basep, pay2, foffg, E, NK, NBC, NBLK);
    aggregate_csr_kernel<<<(NK * 32 + 255) / 256, 256, 0, stream>>>(
        xbf, relbf, pay2, foffg, accbf, NK);

    fused_gemm_mfma_kernel<<<(V + 63) / 64, 256, 0, stream>>>(
        accbf, xbf, wpack, bias, h, stats, V);

    bn_apply_kernel<<<1024, 256, 0, stream>>>(h, stats, bn_gamma, bn_beta, V);
    rel_gemm_kernel<<<(R + 1) / 2, 256, 0, stream>>>(rel_repr, w_rel, out_rel, R);
}

// Round 10
// 160.525 us; speedup vs baseline: 5.1222x; 1.0061x over previous
//
#include <hip/hip_runtime.h>
#include <hip/hip_bf16.h>

// ---------------------------------------------------------------------------
// CompGCN layer:
//   bf16 data plane; coarse-bucket (128 keys) counting sort (low write amp);
//   per-bucket LDS fine sort -> key-sorted payload + per-key CSR;
//   per-key 32-lane register aggregation (high occupancy);
//   bf16-MFMA fused 3-way GEMM (A-frags preloaded -> one latency exposure)
//   with BN-stats epilogue; BN apply + ReLU; out_rel = rel @ w_rel.
// ---------------------------------------------------------------------------

#define SCAN_BLOCK 256
#define CB 128               // keys per coarse bucket
#define CHUNK 4096           // edges per hist/rank block
#define NBC_MAX 800          // >= ceil(2V/CB) = 782
#define CAP 3072             // LDS staging cap per bucket (lambda=1024, 64 sigma)

typedef __attribute__((ext_vector_type(8))) short short8v;   // 8 bf16
typedef __attribute__((ext_vector_type(4))) float float4v;   // MFMA C/D

__device__ inline short f2bf(float f) {
    union { float f; unsigned u; } c; c.f = f;
    unsigned u = c.u;
    return (short)((u + 0x7fffu + ((u >> 16) & 1u)) >> 16);  // RNE
}
__device__ inline float bflo(unsigned u) { return __uint_as_float(u << 16); }
__device__ inline float bfhi(unsigned u) { return __uint_as_float(u & 0xffff0000u); }

// cast x [V,128] and rel [R,128] to bf16, 8 elems/thread
__global__ __launch_bounds__(256) void xcast_kernel(
    const float* __restrict__ x, const float* __restrict__ rel,
    short* __restrict__ xbf, short* __restrict__ relbf, int V, int R)
{
    size_t i = ((size_t)blockIdx.x * 256 + threadIdx.x) * 8;
    size_t nx = (size_t)V * 128;
    size_t total = nx + (size_t)R * 128;
    if (i >= total) return;
    const float* sp; short* dp; size_t k;
    if (i < nx) { sp = x; dp = xbf; k = i; }
    else        { sp = rel; dp = relbf; k = i - nx; }
    float4 v0 = *reinterpret_cast<const float4*>(sp + k);
    float4 v1 = *reinterpret_cast<const float4*>(sp + k + 4);
    short8v o;
    o[0] = f2bf(v0.x); o[1] = f2bf(v0.y); o[2] = f2bf(v0.z); o[3] = f2bf(v0.w);
    o[4] = f2bf(v1.x); o[5] = f2bf(v1.y); o[6] = f2bf(v1.z); o[7] = f2bf(v1.w);
    *reinterpret_cast<short8v*>(dp + k) = o;
}

// per-block LDS histogram over coarse buckets; counts stored BLOCK-MAJOR
__global__ __launch_bounds__(256) void hist_coarse_kernel(
    const int* __restrict__ dst, int* __restrict__ counts,
    int E, int V, int NBC)
{
    __shared__ int lh[NBC_MAX];
    for (int i = threadIdx.x; i < NBC; i += 256) lh[i] = 0;
    __syncthreads();
    int half = E >> 1;
    int e0 = blockIdx.x * CHUNK;
    for (int i = 0; i < CHUNK / 256; ++i) {
        int e = e0 + i * 256 + threadIdx.x;
        if (e < E) {
            int key = dst[e] + (e < half ? 0 : V);
            atomicAdd(&lh[key >> 7], 1);
        }
    }
    __syncthreads();
    for (int i = threadIdx.x; i < NBC; i += 256)
        counts[(size_t)blockIdx.x * NBC + i] = lh[i];
}

// scan phase 1, TRANSPOSED read: logical l = bucket*NBLK + blk
__global__ __launch_bounds__(SCAN_BLOCK) void scan_partial_t_kernel(
    const int* __restrict__ cnt_bm, int* __restrict__ partials,
    int CN, int NBC, int NBLK)
{
    __shared__ int red[SCAN_BLOCK];
    int l = blockIdx.x * SCAN_BLOCK + threadIdx.x;
    int v = 0;
    if (l < CN) {
        int bu = l / NBLK, bl = l - bu * NBLK;
        v = cnt_bm[(size_t)bl * NBC + bu];
    }
    red[threadIdx.x] = v;
    __syncthreads();
    for (int s = SCAN_BLOCK / 2; s > 0; s >>= 1) {
        if (threadIdx.x < s) red[threadIdx.x] += red[threadIdx.x + s];
        __syncthreads();
    }
    if (threadIdx.x == 0) partials[blockIdx.x] = red[0];
}

__global__ __launch_bounds__(1024) void scan_top_kernel(
    int* __restrict__ partials, int NB)
{
    __shared__ int sh[1024];
    int t = threadIdx.x;
    sh[t] = (t < NB) ? partials[t] : 0;
    __syncthreads();
    for (int s = 1; s < 1024; s <<= 1) {
        int v = (t >= s) ? sh[t - s] : 0;
        __syncthreads();
        sh[t] += v;
        __syncthreads();
    }
    if (t < NB) partials[t] = (t == 0) ? 0 : sh[t - 1];
}

__global__ __launch_bounds__(SCAN_BLOCK) void scan_final_t_kernel(
    const int* __restrict__ cnt_bm, const int* __restrict__ partials,
    int* __restrict__ base, int CN, int NBC, int NBLK)
{
    __shared__ int sh[SCAN_BLOCK];
    int l = blockIdx.x * SCAN_BLOCK + threadIdx.x;
    int t = threadIdx.x;
    int v = 0;
    if (l < CN) {
        int bu = l / NBLK, bl = l - bu * NBLK;
        v = cnt_bm[(size_t)bl * NBC + bu];
    }
    sh[t] = v;
    __syncthreads();
    for (int s = 1; s < SCAN_BLOCK; s <<= 1) {
        int u = (t >= s) ? sh[t - s] : 0;
        __syncthreads();
        sh[t] += u;
        __syncthreads();
    }
    if (l < CN) base[l] = partials[blockIdx.x] + sh[t] - v;
}

// scatter payload; per-(bucket,block) runs contiguous, written from one CU.
// payload: (src<<16 | type<<8 | key&127, norm-bits)
__global__ __launch_bounds__(256) void rank_coarse_kernel(
    const int* __restrict__ dst,
    const int* __restrict__ src,
    const int* __restrict__ edge_type,
    const float* __restrict__ edge_norm,
    const int* __restrict__ base,
    uint2* __restrict__ pay,
    int E, int V, int NBC, int NBLK)
{
    __shared__ int lh[NBC_MAX];
    __shared__ int lb[NBC_MAX];
    for (int i = threadIdx.x; i < NBC; i += 256) {
        lh[i] = 0;
        lb[i] = base[(size_t)i * NBLK + blockIdx.x];
    }
    __syncthreads();
    int half = E >> 1;
    int e0 = blockIdx.x * CHUNK;
    for (int i = 0; i < CHUNK / 256; ++i) {
        int e = e0 + i * 256 + threadIdx.x;
        if (e < E) {
            int d = dst[e], s = src[e], t = edge_type[e];
            float n = edge_norm[e];
            int key = d + (e < half ? 0 : V);
            int b = key >> 7;
            int r = atomicAdd(&lh[b], 1);
            pay[lb[b] + r] = make_uint2(
                ((unsigned)s << 16) | ((unsigned)t << 8) | (unsigned)(key & 127),
                __float_as_uint(n));
        }
    }
}

// one block per coarse bucket: LDS counting sort of the bucket's payload;
// writes key-sorted pay2 (coalesced) + per-key CSR foffg [NK+1].
__global__ __launch_bounds__(256) void fine_sort_kernel(
    const uint2* __restrict__ pay,
    const int* __restrict__ base,
    uint2* __restrict__ pay2,
    int* __restrict__ foffg,
    int E, int NK, int NBC, int NBLK)
{
    __shared__ uint2 pay_s[CAP];     // 24 KB
    __shared__ int fcnt[CB];
    __shared__ int ssc[CB];
    __shared__ int fcur[CB];

    int b = blockIdx.x;
    int beg = base[(size_t)b * NBLK];
    int end = (b + 1 < NBC) ? base[(size_t)(b + 1) * NBLK] : E;
    int cnt = end - beg;
    int tid = threadIdx.x;

    if (tid < CB) fcnt[tid] = 0;
    __syncthreads();
    // pass 1: count fine keys (coalesced payload read)
    for (int j = tid; j < cnt; j += 256)
        atomicAdd(&fcnt[pay[beg + j].x & 127u], 1);
    __syncthreads();
    // inclusive scan of fcnt
    if (tid < CB) ssc[tid] = fcnt[tid];
    __syncthreads();
    for (int s = 1; s < CB; s <<= 1) {
        int v = 0;
        if (tid < CB && tid >= s) v = ssc[tid - s];
        __syncthreads();
        if (tid < CB) ssc[tid] += v;
        __syncthreads();
    }
    if (tid < CB) {
        int ex = ssc[tid] - fcnt[tid];
        fcur[tid] = ex;
        int key = b * CB + tid;
        if (key <= NK) foffg[key] = beg + ex;
    }
    __syncthreads();

    if (cnt <= CAP) {
        for (int j = tid; j < cnt; j += 256) {
            uint2 p = pay[beg + j];
            int r = atomicAdd(&fcur[p.x & 127u], 1);
            pay_s[r] = p;
        }
        __syncthreads();
        for (int j = tid; j < cnt; j += 256) pay2[beg + j] = pay_s[j];
    } else {
        for (int j = tid; j < cnt; j += 256) {
            uint2 p = pay[beg + j];
            int r = atomicAdd(&fcur[p.x & 127u], 1);
            pay2[beg + r] = p;
        }
    }
}

// one 32-lane group per key; contiguous payload, register accumulation
__global__ __launch_bounds__(256) void aggregate_csr_kernel(
    const short* __restrict__ xbf,
    const short* __restrict__ relbf,
    const uint2* __restrict__ pay2,
    const int* __restrict__ foffg,
    short* __restrict__ accbf,       // [NK,128]
    int NK)
{
    int gid = (blockIdx.x * 256 + threadIdx.x) >> 5;
    if (gid >= NK) return;
    int lane = threadIdx.x & 31;
    int f0 = lane << 2;

    int beg = foffg[gid], end = foffg[gid + 1];
    float a0 = 0.f, a1 = 0.f, a2 = 0.f, a3 = 0.f;

    for (int bas = beg; bas < end; bas += 32) {
        int j = bas + lane;
        uint2 p = (j < end) ? pay2[j] : make_uint2(0u, 0u);
        int m = min(32, end - bas);
        for (int q = 0; q < m; ++q) {
            unsigned pq = __shfl(p.x, q, 32);
            float nq = __uint_as_float(__shfl(p.y, q, 32));
            int s = (int)(pq >> 16);
            int t = (int)((pq >> 8) & 0xffu);
            uint2 xv = *reinterpret_cast<const uint2*>(xbf + (size_t)s * 128 + f0);
            uint2 rv = *reinterpret_cast<const uint2*>(relbf + (size_t)t * 128 + f0);
            a0 += bflo(xv.x) * bflo(rv.x) * nq;
            a1 += bfhi(xv.x) * bfhi(rv.x) * nq;
            a2 += bflo(xv.y) * bflo(rv.y) * nq;
            a3 += bfhi(xv.y) * bfhi(rv.y) * nq;
        }
    }
    uint2 o;
    o.x = (unsigned)(unsigned short)f2bf(a0) | ((unsigned)(unsigned short)f2bf(a1) << 16);
    o.y = (unsigned)(unsigned short)f2bf(a2) | ((unsigned)(unsigned short)f2bf(a3) << 16);
    *reinterpret_cast<uint2*>(accbf + (size_t)gid * 128 + f0) = o;
}

// pack weights into bf16 MFMA B-fragment order; loop_rel folded into loop_w
__global__ __launch_bounds__(256) void wpack_kernel(
    const float* __restrict__ in_w,
    const float* __restrict__ out_w,
    const float* __restrict__ loop_w,
    const float* __restrict__ loop_rel,
    short* __restrict__ wpack)
{
    int idx = blockIdx.x * 256 + threadIdx.x;
    if (idx >= 3 * 8 * 4 * 64) return;
    int lane = idx & 63;
    int t    = (idx >> 6) & 3;
    int cblk = (idx >> 8) & 7;
    int m    = idx >> 11;
    const float* W = (m == 0) ? in_w : (m == 1) ? out_w : loop_w;
    int col = cblk * 16 + (lane & 15);
    int kb  = t * 32 + ((lane >> 4) << 3);
    short8v v;
#pragma unroll
    for (int j = 0; j < 8; ++j) {
        float w = W[(kb + j) * 128 + col];
        if (m == 2) w *= loop_rel[kb + j];
        v[j] = f2bf(w);
    }
    *reinterpret_cast<short8v*>(wpack + (size_t)idx * 8) = v;
}

// bf16 MFMA fused GEMM + bias + /3, BN stats fused into epilogue.
// All 12 A-fragments preloaded up front: one latency exposure per wave
// instead of twelve (round-9 PMC: MfmaUtil 3%, latency-bound).
__global__ __launch_bounds__(256) void fused_gemm_mfma_kernel(
    const short* __restrict__ accbf,     // [2V,128]
    const short* __restrict__ xbf,       // [V,128]
    const short* __restrict__ wpack,
    const float* __restrict__ bias,
    float* __restrict__ h,
    float* __restrict__ stats,           // [0:128] sum, [128:256] sumsq
    int V)
{
    __shared__ float s_red[256];

    int wave = threadIdx.x >> 6;
    int lane = threadIdx.x & 63;
    int kgrp = lane >> 4;
    int row0 = blockIdx.x * 64 + wave * 16;
    int rowl = row0 + (lane & 15);
    int rowc = min(rowl, V - 1);          // clamp (stores guarded)

    for (int i = threadIdx.x; i < 256; i += 256) s_red[i] = 0.f;

    // preload all A-fragments (12 x short8v = 48 VGPRs), issued back-to-back
    short8v af[3][4];
    {
        const short* A0 = accbf + (size_t)rowc * 128;
        const short* A1 = accbf + (size_t)(V + rowc) * 128;
        const short* A2 = xbf + (size_t)rowc * 128;
#pragma unroll
        for (int t = 0; t < 4; ++t) {
            int o = t * 32 + (kgrp << 3);
            af[0][t] = *reinterpret_cast<const short8v*>(A0 + o);
            af[1][t] = *reinterpret_cast<const short8v*>(A1 + o);
            af[2][t] = *reinterpret_cast<const short8v*>(A2 + o);
        }
    }

    float4v c[8];
#pragma unroll
    for (int b = 0; b < 8; ++b) c[b] = (float4v)(0.f);

#pragma unroll
    for (int m = 0; m < 3; ++m) {
#pragma unroll
        for (int t = 0; t < 4; ++t) {
            const short* wp = wpack + (((size_t)(m * 8) * 4 + t) * 64 + lane) * 8;
#pragma unroll
            for (int b = 0; b < 8; ++b) {
                short8v bf_ = *reinterpret_cast<const short8v*>(wp + (size_t)b * 4 * 64 * 8);
                c[b] = __builtin_amdgcn_mfma_f32_16x16x32_bf16(af[m][t], bf_, c[b], 0, 0, 0);
            }
        }
    }
    __syncthreads();   // s_red zeroed

    // epilogue: C/D layout col=lane&15, row=(lane>>4)*4+r  [m89]
#pragma unroll
    for (int b = 0; b < 8; ++b) {
        int col = b * 16 + (lane & 15);
        float bv = bias[col];
        float ps = 0.f, pq = 0.f;
#pragma unroll
        for (int r = 0; r < 4; ++r) {
            int row = row0 + kgrp * 4 + r;
            if (row < V) {
                float v = c[b][r] * (1.f / 3.f) + bv;
                h[(size_t)row * 128 + col] = v;
                ps += v;
                pq += v * v;
            }
        }
        atomicAdd(&s_red[col], ps);
        atomicAdd(&s_red[128 + col], pq);
    }
    __syncthreads();
    if (threadIdx.x < 256)
        atomicAdd(&stats[threadIdx.x], s_red[threadIdx.x]);
}

__global__ __launch_bounds__(256) void bn_apply_kernel(
    float* __restrict__ h,
    const float* __restrict__ stats,
    const float* __restrict__ gamma,
    const float* __restrict__ beta,
    int V)
{
    int col = threadIdx.x & 127;
    int rg  = threadIdx.x >> 7;
    float inv_v = 1.f / (float)V;
    float mean = stats[col] * inv_v;
    float var  = stats[128 + col] * inv_v - mean * mean;
    float sc = rsqrtf(var + 1e-5f) * gamma[col];
    float sh = beta[col] - mean * sc;
    for (int row = blockIdx.x * 2 + rg; row < V; row += gridDim.x * 2) {
        float v = h[(size_t)row * 128 + col];
        v = v * sc + sh;
        h[(size_t)row * 128 + col] = v > 0.f ? v : 0.f;
    }
}

__global__ __launch_bounds__(256) void rel_gemm_kernel(
    const float* __restrict__ rel,
    const float* __restrict__ w_rel,
    float* __restrict__ out_rel,
    int R)
{
    int col = threadIdx.x & 127;
    int row = blockIdx.x * 2 + (threadIdx.x >> 7);
    if (row >= R) return;
    float acc = 0.f;
    for (int k = 0; k < 128; ++k)
        acc += rel[row * 128 + k] * w_rel[k * 128 + col];
    out_rel[row * 128 + col] = acc;
}

extern "C" void kernel_launch(void* const* d_in, const int* in_sizes, int n_in,
                              void* d_out, int out_size, void* d_ws, size_t ws_size,
                              hipStream_t stream)
{
    const float* x         = (const float*)d_in[0];
    const float* rel_repr  = (const float*)d_in[1];
    const float* edge_norm = (const float*)d_in[2];
    const float* in_w      = (const float*)d_in[3];
    const float* out_w     = (const float*)d_in[4];
    const float* loop_w    = (const float*)d_in[5];
    const float* w_rel     = (const float*)d_in[6];
    const float* loop_rel  = (const float*)d_in[7];
    const float* bias      = (const float*)d_in[8];
    const float* bn_gamma  = (const float*)d_in[9];
    const float* bn_beta   = (const float*)d_in[10];
    const int* edge_type   = (const int*)d_in[11];
    const int* src         = (const int*)d_in[12];
    const int* dst         = (const int*)d_in[13];

    const int V = in_sizes[0] / 128;     // 50000
    const int E = in_sizes[2];           // 800000
    const int R = in_sizes[1] / 128;     // 200
    const int NK = 2 * V;                // keys: [dst(in) ; dst(out)]
    const int NBC = (NK + CB - 1) / CB;              // coarse buckets (782)
    const int NBLK = (E + CHUNK - 1) / CHUNK;        // hist/rank blocks (196)
    const int CN = NBC * NBLK;                       // scan length
    const int NB2 = (CN + SCAN_BLOCK - 1) / SCAN_BLOCK;

    float* h       = (float*)d_out;              // [V,128]
    float* out_rel = h + (size_t)V * 128;        // [R,128]

    // workspace layout
    char* wp_ = (char*)d_ws;
    short* accbf   = (short*)wp_;  wp_ += (size_t)NK * 128 * sizeof(short);
    short* xbf     = (short*)wp_;  wp_ += (size_t)V * 128 * sizeof(short);
    short* relbf   = (short*)wp_;  wp_ += (size_t)R * 128 * sizeof(short);
    short* wpack   = (short*)wp_;  wp_ += (size_t)3 * 8 * 4 * 64 * 8 * sizeof(short);
    float* stats   = (float*)wp_;  wp_ += 256 * sizeof(float);
    int*   counts  = (int*)wp_;    wp_ += (size_t)CN * sizeof(int);   // block-major
    int*   basep   = (int*)wp_;    wp_ += (size_t)CN * sizeof(int);   // bucket-major
    int*   partials= (int*)wp_;    wp_ += 1024 * sizeof(int);
    int*   foffg   = (int*)wp_;    wp_ += ((size_t)NK + 2) * sizeof(int);
    wp_ = (char*)(((uintptr_t)wp_ + 15) & ~(uintptr_t)15);
    uint2* pay     = (uint2*)wp_;  wp_ += (size_t)E * sizeof(uint2);
    uint2* pay2    = (uint2*)wp_;

    // only stats needs zeroing
    hipMemsetAsync(stats, 0, 256 * sizeof(float), stream);

    {
        size_t total = ((size_t)(V + R) * 128) / 8;
        xcast_kernel<<<(int)((total + 255) / 256), 256, 0, stream>>>(
            x, rel_repr, xbf, relbf, V, R);
    }
    wpack_kernel<<<(3 * 8 * 4 * 64 + 255) / 256, 256, 0, stream>>>(
        in_w, out_w, loop_w, loop_rel, wpack);

    hist_coarse_kernel<<<NBLK, 256, 0, stream>>>(dst, counts, E, V, NBC);
    scan_partial_t_kernel<<<NB2, SCAN_BLOCK, 0, stream>>>(counts, partials, CN, NBC, NBLK);
    scan_top_kernel<<<1, 1024, 0, stream>>>(partials, NB2);
    scan_final_t_kernel<<<NB2, SCAN_BLOCK, 0, stream>>>(counts, partials, basep, CN, NBC, NBLK);
    rank_coarse_kernel<<<NBLK, 256, 0, stream>>>(
        dst, src, edge_type, edge_norm, basep, pay, E, V, NBC, NBLK);
    fine_sort_kernel<<<NBC, 256, 0, stream>>>(
        pay, basep, pay2, foffg, E, NK, NBC, NBLK);
    aggregate_csr_kernel<<<(NK * 32 + 255) / 256, 256, 0, stream>>>(
        xbf, relbf, pay2, foffg, accbf, NK);

    fused_gemm_mfma_kernel<<<(V + 63) / 64, 256, 0, stream>>>(
        accbf, xbf, wpack, bias, h, stats, V);

    bn_apply_kernel<<<1024, 256, 0, stream>>>(h, stats, bn_gamma, bn_beta, V);
    rel_gemm_kernel<<<(R + 1) / 2, 256, 0, stream>>>(rel_repr, w_rel, out_rel, R);
}

// Round 11
// 155.898 us; speedup vs baseline: 5.2742x; 1.0297x over previous
//
#include <hip/hip_runtime.h>
#include <hip/hip_bf16.h>

// ---------------------------------------------------------------------------
// CompGCN layer:
//   bf16 data plane; coarse-bucket (128 keys) counting sort (low write amp);
//   per-bucket LDS fine sort -> key-sorted payload + per-key CSR;
//   per-key 32-lane register aggregation (high occupancy);
//   bf16-MFMA fused 3-way GEMM (LDS-staged weights, per-block BN partials);
//   BN reduce; BN apply + ReLU; out_rel = rel @ w_rel.
// ---------------------------------------------------------------------------

#define SCAN_BLOCK 256
#define CB 128               // keys per coarse bucket
#define CHUNK 4096           // edges per hist/rank block
#define NBC_MAX 800          // >= ceil(2V/CB) = 782
#define CAP 3072             // LDS staging cap per bucket (lambda=1024, 64 sigma)

typedef __attribute__((ext_vector_type(8))) short short8v;   // 8 bf16
typedef __attribute__((ext_vector_type(4))) float float4v;   // MFMA C/D

__device__ inline short f2bf(float f) {
    union { float f; unsigned u; } c; c.f = f;
    unsigned u = c.u;
    return (short)((u + 0x7fffu + ((u >> 16) & 1u)) >> 16);  // RNE
}
__device__ inline float bflo(unsigned u) { return __uint_as_float(u << 16); }
__device__ inline float bfhi(unsigned u) { return __uint_as_float(u & 0xffff0000u); }

// cast x [V,128] and rel [R,128] to bf16, 8 elems/thread
__global__ __launch_bounds__(256) void xcast_kernel(
    const float* __restrict__ x, const float* __restrict__ rel,
    short* __restrict__ xbf, short* __restrict__ relbf, int V, int R)
{
    size_t i = ((size_t)blockIdx.x * 256 + threadIdx.x) * 8;
    size_t nx = (size_t)V * 128;
    size_t total = nx + (size_t)R * 128;
    if (i >= total) return;
    const float* sp; short* dp; size_t k;
    if (i < nx) { sp = x; dp = xbf; k = i; }
    else        { sp = rel; dp = relbf; k = i - nx; }
    float4 v0 = *reinterpret_cast<const float4*>(sp + k);
    float4 v1 = *reinterpret_cast<const float4*>(sp + k + 4);
    short8v o;
    o[0] = f2bf(v0.x); o[1] = f2bf(v0.y); o[2] = f2bf(v0.z); o[3] = f2bf(v0.w);
    o[4] = f2bf(v1.x); o[5] = f2bf(v1.y); o[6] = f2bf(v1.z); o[7] = f2bf(v1.w);
    *reinterpret_cast<short8v*>(dp + k) = o;
}

// per-block LDS histogram over coarse buckets; counts stored BLOCK-MAJOR
__global__ __launch_bounds__(256) void hist_coarse_kernel(
    const int* __restrict__ dst, int* __restrict__ counts,
    int E, int V, int NBC)
{
    __shared__ int lh[NBC_MAX];
    for (int i = threadIdx.x; i < NBC; i += 256) lh[i] = 0;
    __syncthreads();
    int half = E >> 1;
    int e0 = blockIdx.x * CHUNK;
    for (int i = 0; i < CHUNK / 256; ++i) {
        int e = e0 + i * 256 + threadIdx.x;
        if (e < E) {
            int key = dst[e] + (e < half ? 0 : V);
            atomicAdd(&lh[key >> 7], 1);
        }
    }
    __syncthreads();
    for (int i = threadIdx.x; i < NBC; i += 256)
        counts[(size_t)blockIdx.x * NBC + i] = lh[i];
}

// scan phase 1, TRANSPOSED read: logical l = bucket*NBLK + blk
__global__ __launch_bounds__(SCAN_BLOCK) void scan_partial_t_kernel(
    const int* __restrict__ cnt_bm, int* __restrict__ partials,
    int CN, int NBC, int NBLK)
{
    __shared__ int red[SCAN_BLOCK];
    int l = blockIdx.x * SCAN_BLOCK + threadIdx.x;
    int v = 0;
    if (l < CN) {
        int bu = l / NBLK, bl = l - bu * NBLK;
        v = cnt_bm[(size_t)bl * NBC + bu];
    }
    red[threadIdx.x] = v;
    __syncthreads();
    for (int s = SCAN_BLOCK / 2; s > 0; s >>= 1) {
        if (threadIdx.x < s) red[threadIdx.x] += red[threadIdx.x + s];
        __syncthreads();
    }
    if (threadIdx.x == 0) partials[blockIdx.x] = red[0];
}

__global__ __launch_bounds__(1024) void scan_top_kernel(
    int* __restrict__ partials, int NB)
{
    __shared__ int sh[1024];
    int t = threadIdx.x;
    sh[t] = (t < NB) ? partials[t] : 0;
    __syncthreads();
    for (int s = 1; s < 1024; s <<= 1) {
        int v = (t >= s) ? sh[t - s] : 0;
        __syncthreads();
        sh[t] += v;
        __syncthreads();
    }
    if (t < NB) partials[t] = (t == 0) ? 0 : sh[t - 1];
}

__global__ __launch_bounds__(SCAN_BLOCK) void scan_final_t_kernel(
    const int* __restrict__ cnt_bm, const int* __restrict__ partials,
    int* __restrict__ base, int CN, int NBC, int NBLK)
{
    __shared__ int sh[SCAN_BLOCK];
    int l = blockIdx.x * SCAN_BLOCK + threadIdx.x;
    int t = threadIdx.x;
    int v = 0;
    if (l < CN) {
        int bu = l / NBLK, bl = l - bu * NBLK;
        v = cnt_bm[(size_t)bl * NBC + bu];
    }
    sh[t] = v;
    __syncthreads();
    for (int s = 1; s < SCAN_BLOCK; s <<= 1) {
        int u = (t >= s) ? sh[t - s] : 0;
        __syncthreads();
        sh[t] += u;
        __syncthreads();
    }
    if (l < CN) base[l] = partials[blockIdx.x] + sh[t] - v;
}

// scatter payload; per-(bucket,block) runs contiguous, written from one CU.
// payload: (src<<16 | type<<8 | key&127, norm-bits)
__global__ __launch_bounds__(256) void rank_coarse_kernel(
    const int* __restrict__ dst,
    const int* __restrict__ src,
    const int* __restrict__ edge_type,
    const float* __restrict__ edge_norm,
    const int* __restrict__ base,
    uint2* __restrict__ pay,
    int E, int V, int NBC, int NBLK)
{
    __shared__ int lh[NBC_MAX];
    __shared__ int lb[NBC_MAX];
    for (int i = threadIdx.x; i < NBC; i += 256) {
        lh[i] = 0;
        lb[i] = base[(size_t)i * NBLK + blockIdx.x];
    }
    __syncthreads();
    int half = E >> 1;
    int e0 = blockIdx.x * CHUNK;
    for (int i = 0; i < CHUNK / 256; ++i) {
        int e = e0 + i * 256 + threadIdx.x;
        if (e < E) {
            int d = dst[e], s = src[e], t = edge_type[e];
            float n = edge_norm[e];
            int key = d + (e < half ? 0 : V);
            int b = key >> 7;
            int r = atomicAdd(&lh[b], 1);
            pay[lb[b] + r] = make_uint2(
                ((unsigned)s << 16) | ((unsigned)t << 8) | (unsigned)(key & 127),
                __float_as_uint(n));
        }
    }
}

// one block per coarse bucket: LDS counting sort of the bucket's payload;
// writes key-sorted pay2 (coalesced) + per-key CSR foffg [NK+1].
__global__ __launch_bounds__(256) void fine_sort_kernel(
    const uint2* __restrict__ pay,
    const int* __restrict__ base,
    uint2* __restrict__ pay2,
    int* __restrict__ foffg,
    int E, int NK, int NBC, int NBLK)
{
    __shared__ uint2 pay_s[CAP];     // 24 KB
    __shared__ int fcnt[CB];
    __shared__ int ssc[CB];
    __shared__ int fcur[CB];

    int b = blockIdx.x;
    int beg = base[(size_t)b * NBLK];
    int end = (b + 1 < NBC) ? base[(size_t)(b + 1) * NBLK] : E;
    int cnt = end - beg;
    int tid = threadIdx.x;

    if (tid < CB) fcnt[tid] = 0;
    __syncthreads();
    // pass 1: count fine keys (coalesced payload read)
    for (int j = tid; j < cnt; j += 256)
        atomicAdd(&fcnt[pay[beg + j].x & 127u], 1);
    __syncthreads();
    // inclusive scan of fcnt
    if (tid < CB) ssc[tid] = fcnt[tid];
    __syncthreads();
    for (int s = 1; s < CB; s <<= 1) {
        int v = 0;
        if (tid < CB && tid >= s) v = ssc[tid - s];
        __syncthreads();
        if (tid < CB) ssc[tid] += v;
        __syncthreads();
    }
    if (tid < CB) {
        int ex = ssc[tid] - fcnt[tid];
        fcur[tid] = ex;
        int key = b * CB + tid;
        if (key <= NK) foffg[key] = beg + ex;
    }
    __syncthreads();

    if (cnt <= CAP) {
        for (int j = tid; j < cnt; j += 256) {
            uint2 p = pay[beg + j];
            int r = atomicAdd(&fcur[p.x & 127u], 1);
            pay_s[r] = p;
        }
        __syncthreads();
        for (int j = tid; j < cnt; j += 256) pay2[beg + j] = pay_s[j];
    } else {
        for (int j = tid; j < cnt; j += 256) {
            uint2 p = pay[beg + j];
            int r = atomicAdd(&fcur[p.x & 127u], 1);
            pay2[beg + r] = p;
        }
    }
}

// one 32-lane group per key; contiguous payload, register accumulation
__global__ __launch_bounds__(256) void aggregate_csr_kernel(
    const short* __restrict__ xbf,
    const short* __restrict__ relbf,
    const uint2* __restrict__ pay2,
    const int* __restrict__ foffg,
    short* __restrict__ accbf,       // [NK,128]
    int NK)
{
    int gid = (blockIdx.x * 256 + threadIdx.x) >> 5;
    if (gid >= NK) return;
    int lane = threadIdx.x & 31;
    int f0 = lane << 2;

    int beg = foffg[gid], end = foffg[gid + 1];
    float a0 = 0.f, a1 = 0.f, a2 = 0.f, a3 = 0.f;

    for (int bas = beg; bas < end; bas += 32) {
        int j = bas + lane;
        uint2 p = (j < end) ? pay2[j] : make_uint2(0u, 0u);
        int m = min(32, end - bas);
        for (int q = 0; q < m; ++q) {
            unsigned pq = __shfl(p.x, q, 32);
            float nq = __uint_as_float(__shfl(p.y, q, 32));
            int s = (int)(pq >> 16);
            int t = (int)((pq >> 8) & 0xffu);
            uint2 xv = *reinterpret_cast<const uint2*>(xbf + (size_t)s * 128 + f0);
            uint2 rv = *reinterpret_cast<const uint2*>(relbf + (size_t)t * 128 + f0);
            a0 += bflo(xv.x) * bflo(rv.x) * nq;
            a1 += bfhi(xv.x) * bfhi(rv.x) * nq;
            a2 += bflo(xv.y) * bflo(rv.y) * nq;
            a3 += bfhi(xv.y) * bfhi(rv.y) * nq;
        }
    }
    uint2 o;
    o.x = (unsigned)(unsigned short)f2bf(a0) | ((unsigned)(unsigned short)f2bf(a1) << 16);
    o.y = (unsigned)(unsigned short)f2bf(a2) | ((unsigned)(unsigned short)f2bf(a3) << 16);
    *reinterpret_cast<uint2*>(accbf + (size_t)gid * 128 + f0) = o;
}

// pack weights into bf16 MFMA B-fragment order; loop_rel folded into loop_w
__global__ __launch_bounds__(256) void wpack_kernel(
    const float* __restrict__ in_w,
    const float* __restrict__ out_w,
    const float* __restrict__ loop_w,
    const float* __restrict__ loop_rel,
    short* __restrict__ wpack)
{
    int idx = blockIdx.x * 256 + threadIdx.x;
    if (idx >= 3 * 8 * 4 * 64) return;
    int lane = idx & 63;
    int t    = (idx >> 6) & 3;
    int cblk = (idx >> 8) & 7;
    int m    = idx >> 11;
    const float* W = (m == 0) ? in_w : (m == 1) ? out_w : loop_w;
    int col = cblk * 16 + (lane & 15);
    int kb  = t * 32 + ((lane >> 4) << 3);
    short8v v;
#pragma unroll
    for (int j = 0; j < 8; ++j) {
        float w = W[(kb + j) * 128 + col];
        if (m == 2) w *= loop_rel[kb + j];
        v[j] = f2bf(w);
    }
    *reinterpret_cast<short8v*>(wpack + (size_t)idx * 8) = v;
}

// bf16 MFMA fused GEMM + bias + /3.
// Weights staged in LDS per block (32 KB per m-phase, 3 phases): B-frags come
// from ds_read_b128 instead of 96 global loads/wave. BN stats written as
// per-block partials (plain stores) -- no global atomic contention.
__global__ __launch_bounds__(256) void fused_gemm_mfma_kernel(
    const short* __restrict__ accbf,     // [2V,128]
    const short* __restrict__ xbf,       // [V,128]
    const short* __restrict__ wpack,
    const float* __restrict__ bias,
    float* __restrict__ h,
    float* __restrict__ stats_part,      // [gridDim.x][256]
    int V)
{
    __shared__ short wlds[8 * 4 * 64 * 8];   // 32 KB: one weight matrix
    __shared__ float s_red[256];

    int tid  = threadIdx.x;
    int wave = tid >> 6;
    int lane = tid & 63;
    int kgrp = lane >> 4;
    int row0 = blockIdx.x * 64 + wave * 16;
    int rowl = row0 + (lane & 15);
    int rowc = min(rowl, V - 1);          // clamp (stores guarded)

    s_red[tid] = 0.f;

    // preload all 12 A-fragments (issued back-to-back, one latency exposure)
    short8v af[3][4];
    {
        const short* A0 = accbf + (size_t)rowc * 128;
        const short* A1 = accbf + (size_t)(V + rowc) * 128;
        const short* A2 = xbf + (size_t)rowc * 128;
#pragma unroll
        for (int t = 0; t < 4; ++t) {
            int o = t * 32 + (kgrp << 3);
            af[0][t] = *reinterpret_cast<const short8v*>(A0 + o);
            af[1][t] = *reinterpret_cast<const short8v*>(A1 + o);
            af[2][t] = *reinterpret_cast<const short8v*>(A2 + o);
        }
    }

    float4v c[8];
#pragma unroll
    for (int b = 0; b < 8; ++b) c[b] = (float4v)(0.f);

    for (int m = 0; m < 3; ++m) {
        __syncthreads();   // wlds reuse (and first-iter: s_red zero visible)
        // stage this matrix's fragments: 2048 x short8v, 8 per thread
        const short8v* wsrc = reinterpret_cast<const short8v*>(wpack + (size_t)m * 8 * 4 * 64 * 8);
        short8v* wdst = reinterpret_cast<short8v*>(wlds);
#pragma unroll
        for (int i = 0; i < 8; ++i)
            wdst[i * 256 + tid] = wsrc[i * 256 + tid];
        __syncthreads();
#pragma unroll
        for (int t = 0; t < 4; ++t) {
#pragma unroll
            for (int b = 0; b < 8; ++b) {
                short8v bf_ = *reinterpret_cast<const short8v*>(wlds + (((b << 2) + t) * 64 + lane) * 8);
                c[b] = __builtin_amdgcn_mfma_f32_16x16x32_bf16(af[m][t], bf_, c[b], 0, 0, 0);
            }
        }
    }
    __syncthreads();

    // epilogue: C/D layout col=lane&15, row=(lane>>4)*4+r  [m89]
#pragma unroll
    for (int b = 0; b < 8; ++b) {
        int col = b * 16 + (lane & 15);
        float bv = bias[col];
        float ps = 0.f, pq = 0.f;
#pragma unroll
        for (int r = 0; r < 4; ++r) {
            int row = row0 + kgrp * 4 + r;
            if (row < V) {
                float v = c[b][r] * (1.f / 3.f) + bv;
                h[(size_t)row * 128 + col] = v;
                ps += v;
                pq += v * v;
            }
        }
        atomicAdd(&s_red[col], ps);
        atomicAdd(&s_red[128 + col], pq);
    }
    __syncthreads();
    stats_part[(size_t)blockIdx.x * 256 + tid] = s_red[tid];
}

// reduce per-block BN partials -> stats[256] (64 atomics per address)
__global__ __launch_bounds__(256) void bn_reduce_kernel(
    const float* __restrict__ stats_part, float* __restrict__ stats, int NB)
{
    int tid = threadIdx.x;
    float s = 0.f;
    for (int i = blockIdx.x; i < NB; i += gridDim.x)
        s += stats_part[(size_t)i * 256 + tid];
    atomicAdd(&stats[tid], s);
}

__global__ __launch_bounds__(256) void bn_apply_kernel(
    float* __restrict__ h,
    const float* __restrict__ stats,
    const float* __restrict__ gamma,
    const float* __restrict__ beta,
    int V)
{
    int col = threadIdx.x & 127;
    int rg  = threadIdx.x >> 7;
    float inv_v = 1.f / (float)V;
    float mean = stats[col] * inv_v;
    float var  = stats[128 + col] * inv_v - mean * mean;
    float sc = rsqrtf(var + 1e-5f) * gamma[col];
    float sh = beta[col] - mean * sc;
    for (int row = blockIdx.x * 2 + rg; row < V; row += gridDim.x * 2) {
        float v = h[(size_t)row * 128 + col];
        v = v * sc + sh;
        h[(size_t)row * 128 + col] = v > 0.f ? v : 0.f;
    }
}

__global__ __launch_bounds__(256) void rel_gemm_kernel(
    const float* __restrict__ rel,
    const float* __restrict__ w_rel,
    float* __restrict__ out_rel,
    int R)
{
    int col = threadIdx.x & 127;
    int row = blockIdx.x * 2 + (threadIdx.x >> 7);
    if (row >= R) return;
    float acc = 0.f;
    for (int k = 0; k < 128; ++k)
        acc += rel[row * 128 + k] * w_rel[k * 128 + col];
    out_rel[row * 128 + col] = acc;
}

extern "C" void kernel_launch(void* const* d_in, const int* in_sizes, int n_in,
                              void* d_out, int out_size, void* d_ws, size_t ws_size,
                              hipStream_t stream)
{
    const float* x         = (const float*)d_in[0];
    const float* rel_repr  = (const float*)d_in[1];
    const float* edge_norm = (const float*)d_in[2];
    const float* in_w      = (const float*)d_in[3];
    const float* out_w     = (const float*)d_in[4];
    const float* loop_w    = (const float*)d_in[5];
    const float* w_rel     = (const float*)d_in[6];
    const float* loop_rel  = (const float*)d_in[7];
    const float* bias      = (const float*)d_in[8];
    const float* bn_gamma  = (const float*)d_in[9];
    const float* bn_beta   = (const float*)d_in[10];
    const int* edge_type   = (const int*)d_in[11];
    const int* src         = (const int*)d_in[12];
    const int* dst         = (const int*)d_in[13];

    const int V = in_sizes[0] / 128;     // 50000
    const int E = in_sizes[2];           // 800000
    const int R = in_sizes[1] / 128;     // 200
    const int NK = 2 * V;                // keys: [dst(in) ; dst(out)]
    const int NBC = (NK + CB - 1) / CB;              // coarse buckets (782)
    const int NBLK = (E + CHUNK - 1) / CHUNK;        // hist/rank blocks (196)
    const int CN = NBC * NBLK;                       // scan length
    const int NB2 = (CN + SCAN_BLOCK - 1) / SCAN_BLOCK;
    const int GEMM_NB = (V + 63) / 64;               // GEMM blocks (782)

    float* h       = (float*)d_out;              // [V,128]
    float* out_rel = h + (size_t)V * 128;        // [R,128]

    // workspace layout
    char* wp_ = (char*)d_ws;
    short* accbf    = (short*)wp_;  wp_ += (size_t)NK * 128 * sizeof(short);
    short* xbf      = (short*)wp_;  wp_ += (size_t)V * 128 * sizeof(short);
    short* relbf    = (short*)wp_;  wp_ += (size_t)R * 128 * sizeof(short);
    short* wpack    = (short*)wp_;  wp_ += (size_t)3 * 8 * 4 * 64 * 8 * sizeof(short);
    float* stats    = (float*)wp_;  wp_ += 256 * sizeof(float);
    float* stats_pt = (float*)wp_;  wp_ += (size_t)GEMM_NB * 256 * sizeof(float);
    int*   counts   = (int*)wp_;    wp_ += (size_t)CN * sizeof(int);   // block-major
    int*   basep    = (int*)wp_;    wp_ += (size_t)CN * sizeof(int);   // bucket-major
    int*   partials = (int*)wp_;    wp_ += 1024 * sizeof(int);
    int*   foffg    = (int*)wp_;    wp_ += ((size_t)NK + 2) * sizeof(int);
    wp_ = (char*)(((uintptr_t)wp_ + 15) & ~(uintptr_t)15);
    uint2* pay      = (uint2*)wp_;  wp_ += (size_t)E * sizeof(uint2);
    uint2* pay2     = (uint2*)wp_;

    // only stats needs zeroing
    hipMemsetAsync(stats, 0, 256 * sizeof(float), stream);

    {
        size_t total = ((size_t)(V + R) * 128) / 8;
        xcast_kernel<<<(int)((total + 255) / 256), 256, 0, stream>>>(
            x, rel_repr, xbf, relbf, V, R);
    }
    wpack_kernel<<<(3 * 8 * 4 * 64 + 255) / 256, 256, 0, stream>>>(
        in_w, out_w, loop_w, loop_rel, wpack);

    hist_coarse_kernel<<<NBLK, 256, 0, stream>>>(dst, counts, E, V, NBC);
    scan_partial_t_kernel<<<NB2, SCAN_BLOCK, 0, stream>>>(counts, partials, CN, NBC, NBLK);
    scan_top_kernel<<<1, 1024, 0, stream>>>(partials, NB2);
    scan_final_t_kernel<<<NB2, SCAN_BLOCK, 0, stream>>>(counts, partials, basep, CN, NBC, NBLK);
    rank_coarse_kernel<<<NBLK, 256, 0, stream>>>(
        dst, src, edge_type, edge_norm, basep, pay, E, V, NBC, NBLK);
    fine_sort_kernel<<<NBC, 256, 0, stream>>>(
        pay, basep, pay2, foffg, E, NK, NBC, NBLK);
    aggregate_csr_kernel<<<(NK * 32 + 255) / 256, 256, 0, stream>>>(
        xbf, relbf, pay2, foffg, accbf, NK);

    fused_gemm_mfma_kernel<<<GEMM_NB, 256, 0, stream>>>(
        accbf, xbf, wpack, bias, h, stats_pt, V);

    bn_reduce_kernel<<<64, 256, 0, stream>>>(stats_pt, stats, GEMM_NB);
    bn_apply_kernel<<<1024, 256, 0, stream>>>(h, stats, bn_gamma, bn_beta, V);
    rel_gemm_kernel<<<(R + 1) / 2, 256, 0, stream>>>(rel_repr, w_rel, out_rel, R);
}